// Round 5
// baseline (5749.379 us; speedup 1.0000x reference)
//
#include <hip/hip_runtime.h>
#include <hip/hip_bf16.h>

typedef _Float16 f16;
typedef f16 f16x8 __attribute__((ext_vector_type(8)));
typedef f16 f16x4 __attribute__((ext_vector_type(4)));
typedef float f32x4 __attribute__((ext_vector_type(4)));

#define MFMA16(a,b,c) __builtin_amdgcn_mfma_f32_16x16x32_f16(a,b,c,0,0,0)

// problem sizes
#define SS 128
#define HH 256
#define NSEQ 512

// workspace byte offsets (WS_NEED unchanged vs round-4: proven to fit)
#define WS_E16   (0)
#define WS_W16   (33554432)
#define WS_SEN   (37224448)
#define WS_U1    (37748736)   // overlay: hg[2] lives here during lstm0
#define WS_H1    (38797312)   // overlay: cnt[32] lives here during lstm0
#define WS_LENS  (38813696)
#define WS_NEED  (38815744)
// lstm1 overlays (e16 region, dead after lstm0): hg2 @0 (16KB), cnt2 @16384

// f16 weight pool element offsets
#define OFF_WIH0F 0
#define OFF_WHH0F 262144
#define OFF_WIH0B 524288
#define OFF_WHH0B 786432
#define OFF_WIH1  1048576
#define OFF_WHH1  1572864

__device__ __forceinline__ float fsig(float x){
  x = fminf(fmaxf(x, -30.f), 30.f);
  float e = __expf(-x);
  return __builtin_amdgcn_rcpf(1.f + e);
}
__device__ __forceinline__ float ftanh(float x){
  x = fminf(fmaxf(x, -15.f), 15.f);
  float e = __expf(2.f * x);
  return (e - 1.f) * __builtin_amdgcn_rcpf(e + 1.f);
}

// ---------------- fused weight f32 -> f16 convert (all 6 matrices) ----------------
__global__ __launch_bounds__(256) void cvt_all_kernel(
    const float* __restrict__ a, const float* __restrict__ b,
    const float* __restrict__ c, const float* __restrict__ d,
    const float* __restrict__ e, const float* __restrict__ f,
    f16* __restrict__ dst){
  const int i = blockIdx.x * 256 + threadIdx.x;  // quad index, grid covers 458752
  const float* s; int off;
  if      (i < 65536)  { s = a; off = i; }
  else if (i < 131072) { s = b; off = i - 65536; }
  else if (i < 196608) { s = c; off = i - 131072; }
  else if (i < 262144) { s = d; off = i - 196608; }
  else if (i < 393216) { s = e; off = i - 262144; }
  else                 { s = f; off = i - 393216; }
  const float4 v = *(const float4*)(s + (size_t)off * 4);
  f16x4 o; o[0] = (f16)v.x; o[1] = (f16)v.y; o[2] = (f16)v.z; o[3] = (f16)v.w;
  *(f16x4*)(dst + (size_t)i * 4) = o;
}

// ---------------- embedding gather -> e16[t][s][k] ----------------
__global__ __launch_bounds__(256) void gather_kernel(const int* __restrict__ x,
                                                     const float* __restrict__ emb,
                                                     f16* __restrict__ e16){
  const int tid = threadIdx.x;
  const int row = blockIdx.x * 4 + (tid >> 6);
  const int l = tid & 63;
  const int t = row >> 9, s = row & 511;
  const int token = x[s * SS + t];
  const float4 v = *(const float4*)(emb + (size_t)token * HH + l * 4);
  f16x4 o; o[0] = (f16)v.x; o[1] = (f16)v.y; o[2] = (f16)v.z; o[3] = (f16)v.w;
  *(f16x4*)(e16 + (size_t)row * HH + l * 4) = o;
}

// ---------------- sequence lengths ----------------
__global__ __launch_bounds__(64) void lens_kernel(const int* __restrict__ xm,
                                                  int* __restrict__ lens){
  const int s = blockIdx.x, l = threadIdx.x;
  const int v0 = (xm[s * SS + l] == 0) ? 1 : 0;
  const int v1 = (xm[s * SS + 64 + l] == 0) ? 1 : 0;
  unsigned long long b0 = __ballot(v0), b1 = __ballot(v1);
  if (l == 0) lens[s] = __popcll(b0) + __popcll(b1);
}

// ---------------- layer-0 bidirectional LSTM, register-resident weights ----------------
// 256 WGs x 256 thr. Cluster = 8 WGs (same XCD via bid%8) = one (dir,32-seq) group.
// WG oct owns hidden j in [oct*32, oct*32+32): its 256 gate rows live in VGPRs.
// Per step: h exchanged via global double buffer + per-cluster counter.
__global__ __launch_bounds__(256, 1) void lstm0_kernel(
    const f16* __restrict__ e16, const f16* __restrict__ w16,
    const float* __restrict__ b0f, const float* __restrict__ b0b,
    const int* __restrict__ lens, f16* __restrict__ hg,
    unsigned int* __restrict__ cnt, f16* __restrict__ sen16)
{
  const int tid = threadIdx.x;
  const int wv = tid >> 6, l = tid & 63;
  const int lrow = l & 15, lgrp = l >> 4;
  const int mh = wv >> 1, jh = wv & 1;

  // bid -> (cluster, oct) with all 8 cluster members on one XCD (xcd = bid%8)
  const int bid = blockIdx.x;
  const int r8 = bid & 7, q = bid >> 3;          // q in [0,32)
  const int cl = r8 + ((q >> 3) << 3);           // cluster 0..31
  const int oct = q & 7;                         // member 0..7
  const int dir = cl >> 4;
  const int sbase = (cl & 15) * 32;              // seq base within dir
  const int dsbase = dir * 512 + sbase;          // dir-seq base

  const f16* __restrict__ Wih = w16 + (dir ? OFF_WIH0B : OFF_WIH0F);
  const f16* __restrict__ Whh = w16 + (dir ? OFF_WHH0B : OFF_WHH0F);
  const float* __restrict__ bias = dir ? b0b : b0f;

  const int jglob = oct * 32 + jh * 16 + lrow;   // hidden channel 0..255

  // register-resident weight fragments: B[g][kk]; kk<8 = Whh part, kk>=8 = Wih part
  f16x8 B[4][16];
  #pragma unroll
  for (int g = 0; g < 4; ++g){
    const int grow = g * 256 + jglob;
    const f16* ph = Whh + (size_t)grow * HH + lgrp * 8;
    const f16* pi = Wih + (size_t)grow * HH + lgrp * 8;
    #pragma unroll
    for (int kk = 0; kk < 8; ++kk) B[g][kk]   = *(const f16x8*)(ph + kk * 32);
    #pragma unroll
    for (int kk = 0; kk < 8; ++kk) B[g][kk+8] = *(const f16x8*)(pi + kk * 32);
  }

  float bv[4];
  #pragma unroll
  for (int g = 0; g < 4; ++g) bv[g] = bias[g * 256 + jglob];
  int len4[4];
  #pragma unroll
  for (int r = 0; r < 4; ++r) len4[r] = lens[sbase + mh * 16 + lgrp * 4 + r];

  float c4[4] = {}, h4[4] = {};
  const unsigned int* cp = cnt + cl;

  for (int tt = 0; tt < SS; ++tt){
    const int t = dir ? (SS - 1 - tt) : tt;
    f16x8 A[16];
    // e-part of A (independent of h): issue before the spin
    const f16* ep = e16 + ((size_t)(t * NSEQ + sbase + mh * 16 + lrow)) * HH + lgrp * 8;
    #pragma unroll
    for (int kk = 0; kk < 8; ++kk) A[kk + 8] = *(const f16x8*)(ep + kk * 32);

    if (tt > 0){
      const unsigned int need = 8u * (unsigned)tt;
      while (__hip_atomic_load(cp, __ATOMIC_ACQUIRE, __HIP_MEMORY_SCOPE_AGENT) < need)
        __builtin_amdgcn_s_sleep(1);
    }
    const f16* hp = hg + (size_t)(tt & 1) * 262144
                       + (size_t)(dsbase + mh * 16 + lrow) * HH + lgrp * 8;
    #pragma unroll
    for (int kk = 0; kk < 8; ++kk) A[kk] = *(const f16x8*)(hp + kk * 32);

    f32x4 ac[4];
    #pragma unroll
    for (int g = 0; g < 4; ++g){ ac[g][0]=0.f; ac[g][1]=0.f; ac[g][2]=0.f; ac[g][3]=0.f; }
    #pragma unroll
    for (int kk = 0; kk < 16; ++kk){
      ac[0] = MFMA16(A[kk], B[0][kk], ac[0]);
      ac[1] = MFMA16(A[kk], B[1][kk], ac[1]);
      ac[2] = MFMA16(A[kk], B[2][kk], ac[2]);
      ac[3] = MFMA16(A[kk], B[3][kk], ac[3]);
    }

    f16* hw = hg + (size_t)((tt + 1) & 1) * 262144
                 + (size_t)(dsbase + mh * 16 + lgrp * 4) * HH + jglob;
    #pragma unroll
    for (int r = 0; r < 4; ++r){
      const float iv = fsig (ac[0][r] + bv[0]);
      const float fv = fsig (ac[1][r] + bv[1]);
      const float gv = ftanh(ac[2][r] + bv[2]);
      const float ov = fsig (ac[3][r] + bv[3]);
      const float cn = fv * c4[r] + iv * gv;
      const float hn = ov * ftanh(cn);
      const bool vld = (t < len4[r]);
      c4[r] = vld ? cn : c4[r];
      h4[r] = vld ? hn : h4[r];
      hw[(size_t)r * HH] = (f16)h4[r];
    }
    __threadfence();
    __syncthreads();
    if (tid == 0)
      __hip_atomic_fetch_add((unsigned int*)cp, 1u, __ATOMIC_RELEASE, __HIP_MEMORY_SCOPE_AGENT);
  }

  #pragma unroll
  for (int r = 0; r < 4; ++r){
    const int s = sbase + mh * 16 + lgrp * 4 + r;
    sen16[(size_t)((s & 31) * 16 + (s >> 5)) * 512 + dir * 256 + jglob] = (f16)h4[r];
  }
}

// ---------------- layer-1 input GEMM: U1[p][gcol][b] ----------------
__global__ __launch_bounds__(256, 2) void u1_gemm_kernel(
    const f16* __restrict__ sen16, const f16* __restrict__ w16, f16* __restrict__ U1)
{
  const int tid = threadIdx.x;
  const int w = tid >> 6, l = tid & 63, lrow = l & 15, lgrp = l >> 4;
  const int p = blockIdx.x;
  const f16* __restrict__ Wih1 = w16 + OFF_WIH1;

  f16x8 A[16];
  #pragma unroll
  for (int kb = 0; kb < 16; ++kb)
    A[kb] = *(const f16x8*)&sen16[(size_t)(p * 16 + lrow) * 512 + kb * 32 + lgrp * 8];

  for (int tile = 0; tile < 16; ++tile){
    const int col = (w * 16 + tile) * 16 + lrow;
    const f16* wp = Wih1 + (size_t)col * 512 + lgrp * 8;
    f32x4 acc = {0.f,0.f,0.f,0.f};
    #pragma unroll
    for (int kb = 0; kb < 16; ++kb){
      f16x8 bfrag = *(const f16x8*)(wp + kb * 32);
      acc = MFMA16(A[kb], bfrag, acc);
    }
    f16x4 o4;
    #pragma unroll
    for (int r = 0; r < 4; ++r) o4[r] = (f16)acc[r];
    *(f16x4*)&U1[((size_t)p * 1024 + col) * 16 + lgrp * 4] = o4;
  }
}

// ---------------- layer-1 LSTM, register-resident Whh1, 8-WG cluster on XCD0 ----------------
// grid 64 x 128thr; only bid%8==0 work (8 WGs, all xcd0). WG oct owns j in [oct*32,+32).
__global__ __launch_bounds__(128, 1) void lstm1_kernel(
    const f16* __restrict__ w16, const f16* __restrict__ U1,
    const float* __restrict__ b1, f16* __restrict__ hg2,
    unsigned int* __restrict__ cnt2, float* __restrict__ h1)
{
  const int bid = blockIdx.x;
  if (bid & 7) return;
  const int oct = bid >> 3;
  const int tid = threadIdx.x;
  const int jh = tid >> 6, l = tid & 63;
  const int lrow = l & 15, lgrp = l >> 4;
  const int jglob = oct * 32 + jh * 16 + lrow;
  const f16* __restrict__ Whh = w16 + OFF_WHH1;

  f16x8 B[4][8];
  #pragma unroll
  for (int g = 0; g < 4; ++g){
    const f16* ph = Whh + (size_t)(g * 256 + jglob) * HH + lgrp * 8;
    #pragma unroll
    for (int kk = 0; kk < 8; ++kk) B[g][kk] = *(const f16x8*)(ph + kk * 32);
  }
  float bv[4];
  #pragma unroll
  for (int g = 0; g < 4; ++g) bv[g] = b1[g * 256 + jglob];

  float c4[4] = {}, h4[4] = {};

  for (int pt = 0; pt < 32; ++pt){
    if (pt > 0){
      const unsigned int need = 8u * (unsigned)pt;
      while (__hip_atomic_load(cnt2, __ATOMIC_ACQUIRE, __HIP_MEMORY_SCOPE_AGENT) < need)
        __builtin_amdgcn_s_sleep(1);
    }
    f16x8 A[8];
    const f16* hp = hg2 + (size_t)(pt & 1) * 4096 + (size_t)lrow * HH + lgrp * 8;
    #pragma unroll
    for (int kk = 0; kk < 8; ++kk) A[kk] = *(const f16x8*)(hp + kk * 32);

    f32x4 ac[4];
    #pragma unroll
    for (int g = 0; g < 4; ++g){ ac[g][0]=0.f; ac[g][1]=0.f; ac[g][2]=0.f; ac[g][3]=0.f; }
    #pragma unroll
    for (int kk = 0; kk < 8; ++kk){
      ac[0] = MFMA16(A[kk], B[0][kk], ac[0]);
      ac[1] = MFMA16(A[kk], B[1][kk], ac[1]);
      ac[2] = MFMA16(A[kk], B[2][kk], ac[2]);
      ac[3] = MFMA16(A[kk], B[3][kk], ac[3]);
    }

    f16x4 u[4];
    #pragma unroll
    for (int g = 0; g < 4; ++g)
      u[g] = *(const f16x4*)&U1[((size_t)pt * 1024 + g * 256 + jglob) * 16 + lgrp * 4];

    f16* hw = hg2 + (size_t)((pt + 1) & 1) * 4096 + (size_t)(lgrp * 4) * HH + jglob;
    #pragma unroll
    for (int r = 0; r < 4; ++r){
      const float iv = fsig (ac[0][r] + (float)u[0][r] + bv[0]);
      const float fv = fsig (ac[1][r] + (float)u[1][r] + bv[1]);
      const float gv = ftanh(ac[2][r] + (float)u[2][r] + bv[2]);
      const float ov = fsig (ac[3][r] + (float)u[3][r] + bv[3]);
      const float cn = fv * c4[r] + iv * gv;
      c4[r] = cn;
      h4[r] = ov * ftanh(cn);
      hw[(size_t)r * HH] = (f16)h4[r];
    }
    __threadfence();
    __syncthreads();
    if (tid == 0)
      __hip_atomic_fetch_add(cnt2, 1u, __ATOMIC_RELEASE, __HIP_MEMORY_SCOPE_AGENT);
  }

  #pragma unroll
  for (int r = 0; r < 4; ++r)
    h1[(lgrp * 4 + r) * 256 + jglob] = h4[r];
}

// ---------------- final FC ----------------
__global__ __launch_bounds__(256) void fc_kernel(const float* __restrict__ h1,
                                                 const float* __restrict__ Wfc,
                                                 const float* __restrict__ bfc,
                                                 float* __restrict__ out){
  __shared__ float hl[16 * 256];
  const int tid = threadIdx.x;
  for (int i = tid; i < 4096; i += 256) hl[i] = h1[i];
  __syncthreads();
  const int o = tid & 127, half = tid >> 7;
  float acc[8];
  #pragma unroll
  for (int i = 0; i < 8; ++i) acc[i] = bfc[o];
  const float* wp = Wfc + (size_t)o * 256;
  for (int j = 0; j < 256; ++j){
    const float wv = wp[j];
    #pragma unroll
    for (int i = 0; i < 8; ++i) acc[i] += wv * hl[(half * 8 + i) * 256 + j];
  }
  #pragma unroll
  for (int i = 0; i < 8; ++i) out[(half * 8 + i) * 128 + o] = acc[i];
}

extern "C" void kernel_launch(void* const* d_in, const int* in_sizes, int n_in,
                              void* d_out, int out_size, void* d_ws, size_t ws_size,
                              hipStream_t stream) {
  if (ws_size < (size_t)WS_NEED) return;

  const int*   x     = (const int*)  d_in[0];
  const int*   xm    = (const int*)  d_in[1];
  const float* emb   = (const float*)d_in[2];
  const float* Wih0f = (const float*)d_in[3];
  const float* Whh0f = (const float*)d_in[4];
  const float* b0f   = (const float*)d_in[5];
  const float* Wih0b = (const float*)d_in[6];
  const float* Whh0b = (const float*)d_in[7];
  const float* b0b   = (const float*)d_in[8];
  const float* Wih1  = (const float*)d_in[9];
  const float* Whh1  = (const float*)d_in[10];
  const float* b1    = (const float*)d_in[11];
  const float* Wfc   = (const float*)d_in[12];
  const float* bfc   = (const float*)d_in[13];
  float* out = (float*)d_out;
  char*  ws  = (char*)d_ws;

  f16*   e16   = (f16*)(ws + WS_E16);
  f16*   w16   = (f16*)(ws + WS_W16);
  f16*   sen16 = (f16*)(ws + WS_SEN);
  f16*   U1    = (f16*)(ws + WS_U1);
  float* h1    = (float*)(ws + WS_H1);
  int*   lens  = (int*)(ws + WS_LENS);
  // lstm0 overlays (dead before u1_gemm/lstm1 run)
  f16*          hg0  = (f16*)(ws + WS_U1);
  unsigned int* cnt0 = (unsigned int*)(ws + WS_H1);
  // lstm1 overlays (e16 region, dead after lstm0)
  f16*          hg2  = (f16*)(ws + 0);
  unsigned int* cnt2 = (unsigned int*)(ws + 16384);

  cvt_all_kernel<<<1792, 256, 0, stream>>>(Wih0f, Whh0f, Wih0b, Whh0b, Wih1, Whh1, w16);
  gather_kernel<<<16384, 256, 0, stream>>>(x, emb, e16);
  lens_kernel<<<512, 64, 0, stream>>>(xm, lens);

  hipMemsetAsync(ws + WS_U1, 0, 524288, stream);  // hg[0] = h(0) = 0
  hipMemsetAsync(ws + WS_H1, 0, 128, stream);     // cnt[32] = 0
  lstm0_kernel<<<256, 256, 0, stream>>>(e16, w16, b0f, b0b, lens, hg0, cnt0, sen16);

  hipMemsetAsync(ws + 0, 0, 16512, stream);       // hg2[2] + cnt2 = 0
  u1_gemm_kernel<<<32, 256, 0, stream>>>(sen16, w16, U1);
  lstm1_kernel<<<64, 128, 0, stream>>>(w16, U1, b1, hg2, cnt2, h1);
  fc_kernel<<<1, 256, 0, stream>>>(h1, Wfc, bfc, out);
}

// Round 6
// 3505.544 us; speedup vs baseline: 1.6401x; 1.6401x over previous
//
#include <hip/hip_runtime.h>
#include <hip/hip_bf16.h>

typedef _Float16 f16;
typedef f16 f16x8 __attribute__((ext_vector_type(8)));
typedef f16 f16x4 __attribute__((ext_vector_type(4)));
typedef float f32x4 __attribute__((ext_vector_type(4)));

#define MFMA16(a,b,c) __builtin_amdgcn_mfma_f32_16x16x32_f16(a,b,c,0,0,0)

// problem sizes
#define SS 128
#define HH 256
#define NSEQ 512

// workspace byte offsets
#define WS_E16   (0)
#define WS_W16   (33554432)
#define WS_SEN   (37224448)
#define WS_U1    (37748736)
#define WS_H1    (38797312)
#define WS_LENS  (38813696)
#define WS_NEED  (38815744)

// f16 weight pool element offsets
#define OFF_WIH0F 0
#define OFF_WHH0F 262144
#define OFF_WIH0B 524288
#define OFF_WHH0B 786432
#define OFF_WIH1  1048576
#define OFF_WHH1  1572864

__device__ __forceinline__ float fsig(float x){
  // no clamp needed: exp(inf)->inf -> rcp -> 0; exp(-inf)->0 -> 1. No NaN for finite x.
  float e = __expf(-x);
  return __builtin_amdgcn_rcpf(1.f + e);
}
__device__ __forceinline__ float ftanh(float x){
  x = fminf(fmaxf(x, -15.f), 15.f);   // clamp required: (inf-1)*rcp(inf+1) = NaN
  float e = __expf(2.f * x);
  return (e - 1.f) * __builtin_amdgcn_rcpf(e + 1.f);
}

// ---------------- fused weight f32 -> f16 convert (all 6 matrices) ----------------
__global__ __launch_bounds__(256) void cvt_all_kernel(
    const float* __restrict__ a, const float* __restrict__ b,
    const float* __restrict__ c, const float* __restrict__ d,
    const float* __restrict__ e, const float* __restrict__ f,
    f16* __restrict__ dst){
  const int i = blockIdx.x * 256 + threadIdx.x;  // quad index, grid covers 458752
  const float* s; int off;
  if      (i < 65536)  { s = a; off = i; }
  else if (i < 131072) { s = b; off = i - 65536; }
  else if (i < 196608) { s = c; off = i - 131072; }
  else if (i < 262144) { s = d; off = i - 196608; }
  else if (i < 393216) { s = e; off = i - 262144; }
  else                 { s = f; off = i - 393216; }
  const float4 v = *(const float4*)(s + (size_t)off * 4);
  f16x4 o; o[0] = (f16)v.x; o[1] = (f16)v.y; o[2] = (f16)v.z; o[3] = (f16)v.w;
  *(f16x4*)(dst + (size_t)i * 4) = o;
}

// ---------------- embedding gather -> e16[t][s][k] ----------------
__global__ __launch_bounds__(256) void gather_kernel(const int* __restrict__ x,
                                                     const float* __restrict__ emb,
                                                     f16* __restrict__ e16){
  const int tid = threadIdx.x;
  const int row = blockIdx.x * 4 + (tid >> 6);
  const int l = tid & 63;
  const int t = row >> 9, s = row & 511;
  const int token = x[s * SS + t];
  const float4 v = *(const float4*)(emb + (size_t)token * HH + l * 4);
  f16x4 o; o[0] = (f16)v.x; o[1] = (f16)v.y; o[2] = (f16)v.z; o[3] = (f16)v.w;
  *(f16x4*)(e16 + (size_t)row * HH + l * 4) = o;
}

// ---------------- sequence lengths ----------------
__global__ __launch_bounds__(64) void lens_kernel(const int* __restrict__ xm,
                                                  int* __restrict__ lens){
  const int s = blockIdx.x, l = threadIdx.x;
  const int v0 = (xm[s * SS + l] == 0) ? 1 : 0;
  const int v1 = (xm[s * SS + 64 + l] == 0) ? 1 : 0;
  unsigned long long b0 = __ballot(v0), b1 = __ballot(v1);
  if (l == 0) lens[s] = __popcll(b0) + __popcll(b1);
}

// ---------------- layer-0 bidirectional LSTM ----------------
// 64 WGs x 1024 threads (16 waves). WG = (dir, 16 sequences) — whole recurrence
// in ONE workgroup: no cross-WG sync. Wave w owns hidden j in [w*16, w*16+16);
// its Whh+Wih gate rows (4g x 16j x 512K) live in 256 VGPRs, loaded once.
// h exchanged via LDS double buffer, ONE __syncthreads per step.
__global__ __launch_bounds__(1024, 1) void lstm0_kernel(
    const f16* __restrict__ e16, const f16* __restrict__ w16,
    const float* __restrict__ b0f, const float* __restrict__ b0b,
    const int* __restrict__ lens, f16* __restrict__ sen16)
{
  __shared__ f16 hbuf[2][16][264];
  const int tid = threadIdx.x;
  const int w = tid >> 6, l = tid & 63;
  const int lrow = l & 15, lgrp = l >> 4;
  const int bid = blockIdx.x;
  const int dir = bid >> 5, sbase = (bid & 31) * 16;

  const f16* __restrict__ Wih = w16 + (dir ? OFF_WIH0B : OFF_WIH0F);
  const f16* __restrict__ Whh = w16 + (dir ? OFF_WHH0B : OFF_WHH0F);
  const float* __restrict__ bias = dir ? b0b : b0f;

  // register-resident weights: B[g][kk]; kk<8 = Whh k-chunk, kk>=8 = Wih k-chunk
  f16x8 B[4][16];
  #pragma unroll
  for (int g = 0; g < 4; ++g){
    const int grow = g * 256 + w * 16 + lrow;
    const f16* ph = Whh + (size_t)grow * HH + lgrp * 8;
    const f16* pi = Wih + (size_t)grow * HH + lgrp * 8;
    #pragma unroll
    for (int kk = 0; kk < 8; ++kk) B[g][kk]     = *(const f16x8*)(ph + kk * 32);
    #pragma unroll
    for (int kk = 0; kk < 8; ++kk) B[g][kk + 8] = *(const f16x8*)(pi + kk * 32);
  }

  float bv[4];
  #pragma unroll
  for (int g = 0; g < 4; ++g) bv[g] = bias[g * 256 + w * 16 + lrow];
  int len4[4];
  #pragma unroll
  for (int r = 0; r < 4; ++r) len4[r] = lens[sbase + lgrp * 4 + r];

  for (int i = tid; i < 2 * 16 * 264; i += 1024) ((f16*)hbuf)[i] = (f16)0.f;
  float c4[4] = {}, h4[4] = {};
  __syncthreads();

  for (int tt = 0; tt < SS; ++tt){
    const int t = dir ? (SS - 1 - tt) : tt;
    const int cur = tt & 1, nxt = cur ^ 1;

    f16x8 A[16];
    // e-part (global, L2-hot): issue first so latency hides under h-MFMAs
    const f16* ep = e16 + ((size_t)(t * NSEQ + sbase + lrow)) * HH + lgrp * 8;
    #pragma unroll
    for (int kk = 0; kk < 8; ++kk) A[kk + 8] = *(const f16x8*)(ep + kk * 32);
    // h-part from LDS
    #pragma unroll
    for (int kk = 0; kk < 8; ++kk)
      A[kk] = *(const f16x8*)&hbuf[cur][lrow][kk * 32 + lgrp * 8];

    f32x4 ac[4];
    #pragma unroll
    for (int g = 0; g < 4; ++g){ ac[g][0]=0.f; ac[g][1]=0.f; ac[g][2]=0.f; ac[g][3]=0.f; }
    #pragma unroll
    for (int kk = 0; kk < 16; ++kk){
      ac[0] = MFMA16(A[kk], B[0][kk], ac[0]);
      ac[1] = MFMA16(A[kk], B[1][kk], ac[1]);
      ac[2] = MFMA16(A[kk], B[2][kk], ac[2]);
      ac[3] = MFMA16(A[kk], B[3][kk], ac[3]);
    }

    #pragma unroll
    for (int r = 0; r < 4; ++r){
      const float iv = fsig (ac[0][r] + bv[0]);
      const float fv = fsig (ac[1][r] + bv[1]);
      const float gv = ftanh(ac[2][r] + bv[2]);
      const float ov = fsig (ac[3][r] + bv[3]);
      const float cn = fv * c4[r] + iv * gv;
      const float hn = ov * ftanh(cn);
      const bool vld = (t < len4[r]);
      c4[r] = vld ? cn : c4[r];
      h4[r] = vld ? hn : h4[r];
      hbuf[nxt][lgrp * 4 + r][w * 16 + lrow] = (f16)h4[r];
    }
    __syncthreads();  // single barrier: nxt-writes visible; cur-reads done (own lgkmcnt drained at barrier)
  }

  #pragma unroll
  for (int r = 0; r < 4; ++r){
    const int s = sbase + lgrp * 4 + r;
    sen16[(size_t)((s & 31) * 16 + (s >> 5)) * 512 + dir * 256 + w * 16 + lrow] = (f16)h4[r];
  }
}

// ---------------- layer-1 input GEMM: U1[p][gcol][b] ----------------
__global__ __launch_bounds__(256, 2) void u1_gemm_kernel(
    const f16* __restrict__ sen16, const f16* __restrict__ w16, f16* __restrict__ U1)
{
  const int tid = threadIdx.x;
  const int w = tid >> 6, l = tid & 63, lrow = l & 15, lgrp = l >> 4;
  const int p = blockIdx.x;
  const f16* __restrict__ Wih1 = w16 + OFF_WIH1;

  f16x8 A[16];
  #pragma unroll
  for (int kb = 0; kb < 16; ++kb)
    A[kb] = *(const f16x8*)&sen16[(size_t)(p * 16 + lrow) * 512 + kb * 32 + lgrp * 8];

  for (int tile = 0; tile < 16; ++tile){
    const int col = (w * 16 + tile) * 16 + lrow;
    const f16* wp = Wih1 + (size_t)col * 512 + lgrp * 8;
    f32x4 acc = {0.f,0.f,0.f,0.f};
    #pragma unroll
    for (int kb = 0; kb < 16; ++kb){
      f16x8 bfrag = *(const f16x8*)(wp + kb * 32);
      acc = MFMA16(A[kb], bfrag, acc);
    }
    f16x4 o4;
    #pragma unroll
    for (int r = 0; r < 4; ++r) o4[r] = (f16)acc[r];
    *(f16x4*)&U1[((size_t)p * 1024 + col) * 16 + lgrp * 4] = o4;
  }
}

// ---------------- layer-1 LSTM: ONE WG x 1024 thr, register-resident Whh1 ----------------
__global__ __launch_bounds__(1024, 1) void lstm1_kernel(
    const f16* __restrict__ w16, const f16* __restrict__ U1,
    const float* __restrict__ b1, float* __restrict__ h1)
{
  __shared__ f16 hbuf[2][16][264];
  const int tid = threadIdx.x;
  const int w = tid >> 6, l = tid & 63;
  const int lrow = l & 15, lgrp = l >> 4;
  const int jglob = w * 16 + lrow;
  const f16* __restrict__ Whh = w16 + OFF_WHH1;

  f16x8 B[4][8];
  #pragma unroll
  for (int g = 0; g < 4; ++g){
    const f16* ph = Whh + (size_t)(g * 256 + jglob) * HH + lgrp * 8;
    #pragma unroll
    for (int kk = 0; kk < 8; ++kk) B[g][kk] = *(const f16x8*)(ph + kk * 32);
  }
  float bv[4];
  #pragma unroll
  for (int g = 0; g < 4; ++g) bv[g] = b1[g * 256 + jglob];

  for (int i = tid; i < 2 * 16 * 264; i += 1024) ((f16*)hbuf)[i] = (f16)0.f;
  float c4[4] = {}, h4[4] = {};
  __syncthreads();

  for (int pt = 0; pt < 32; ++pt){
    const int cur = pt & 1, nxt = cur ^ 1;
    f16x8 A[8];
    #pragma unroll
    for (int kk = 0; kk < 8; ++kk)
      A[kk] = *(const f16x8*)&hbuf[cur][lrow][kk * 32 + lgrp * 8];

    f32x4 ac[4];
    #pragma unroll
    for (int g = 0; g < 4; ++g){ ac[g][0]=0.f; ac[g][1]=0.f; ac[g][2]=0.f; ac[g][3]=0.f; }
    #pragma unroll
    for (int kk = 0; kk < 8; ++kk){
      ac[0] = MFMA16(A[kk], B[0][kk], ac[0]);
      ac[1] = MFMA16(A[kk], B[1][kk], ac[1]);
      ac[2] = MFMA16(A[kk], B[2][kk], ac[2]);
      ac[3] = MFMA16(A[kk], B[3][kk], ac[3]);
    }

    f16x4 u[4];
    #pragma unroll
    for (int g = 0; g < 4; ++g)
      u[g] = *(const f16x4*)&U1[((size_t)pt * 1024 + g * 256 + jglob) * 16 + lgrp * 4];

    #pragma unroll
    for (int r = 0; r < 4; ++r){
      const float iv = fsig (ac[0][r] + (float)u[0][r] + bv[0]);
      const float fv = fsig (ac[1][r] + (float)u[1][r] + bv[1]);
      const float gv = ftanh(ac[2][r] + (float)u[2][r] + bv[2]);
      const float ov = fsig (ac[3][r] + (float)u[3][r] + bv[3]);
      const float cn = fv * c4[r] + iv * gv;
      c4[r] = cn;
      h4[r] = ov * ftanh(cn);
      hbuf[nxt][lgrp * 4 + r][jglob] = (f16)h4[r];
    }
    __syncthreads();
  }

  #pragma unroll
  for (int r = 0; r < 4; ++r)
    h1[(lgrp * 4 + r) * 256 + jglob] = h4[r];
}

// ---------------- final FC ----------------
__global__ __launch_bounds__(256) void fc_kernel(const float* __restrict__ h1,
                                                 const float* __restrict__ Wfc,
                                                 const float* __restrict__ bfc,
                                                 float* __restrict__ out){
  __shared__ float hl[16 * 256];
  const int tid = threadIdx.x;
  for (int i = tid; i < 4096; i += 256) hl[i] = h1[i];
  __syncthreads();
  const int o = tid & 127, half = tid >> 7;
  float acc[8];
  #pragma unroll
  for (int i = 0; i < 8; ++i) acc[i] = bfc[o];
  const float* wp = Wfc + (size_t)o * 256;
  for (int j = 0; j < 256; ++j){
    const float wv = wp[j];
    #pragma unroll
    for (int i = 0; i < 8; ++i) acc[i] += wv * hl[(half * 8 + i) * 256 + j];
  }
  #pragma unroll
  for (int i = 0; i < 8; ++i) out[(half * 8 + i) * 128 + o] = acc[i];
}

extern "C" void kernel_launch(void* const* d_in, const int* in_sizes, int n_in,
                              void* d_out, int out_size, void* d_ws, size_t ws_size,
                              hipStream_t stream) {
  if (ws_size < (size_t)WS_NEED) return;

  const int*   x     = (const int*)  d_in[0];
  const int*   xm    = (const int*)  d_in[1];
  const float* emb   = (const float*)d_in[2];
  const float* Wih0f = (const float*)d_in[3];
  const float* Whh0f = (const float*)d_in[4];
  const float* b0f   = (const float*)d_in[5];
  const float* Wih0b = (const float*)d_in[6];
  const float* Whh0b = (const float*)d_in[7];
  const float* b0b   = (const float*)d_in[8];
  const float* Wih1  = (const float*)d_in[9];
  const float* Whh1  = (const float*)d_in[10];
  const float* b1    = (const float*)d_in[11];
  const float* Wfc   = (const float*)d_in[12];
  const float* bfc   = (const float*)d_in[13];
  float* out = (float*)d_out;
  char*  ws  = (char*)d_ws;

  f16*   e16   = (f16*)(ws + WS_E16);
  f16*   w16   = (f16*)(ws + WS_W16);
  f16*   sen16 = (f16*)(ws + WS_SEN);
  f16*   U1    = (f16*)(ws + WS_U1);
  float* h1    = (float*)(ws + WS_H1);
  int*   lens  = (int*)(ws + WS_LENS);

  cvt_all_kernel<<<1792, 256, 0, stream>>>(Wih0f, Whh0f, Wih0b, Whh0b, Wih1, Whh1, w16);
  gather_kernel<<<16384, 256, 0, stream>>>(x, emb, e16);
  lens_kernel<<<512, 64, 0, stream>>>(xm, lens);

  lstm0_kernel<<<64, 1024, 0, stream>>>(e16, w16, b0f, b0b, lens, sen16);
  u1_gemm_kernel<<<32, 256, 0, stream>>>(sen16, w16, U1);
  lstm1_kernel<<<1, 1024, 0, stream>>>(w16, U1, b1, h1);
  fc_kernel<<<1, 256, 0, stream>>>(h1, Wfc, bfc, out);
}

// Round 8
// 2677.923 us; speedup vs baseline: 2.1470x; 1.3091x over previous
//
#include <hip/hip_runtime.h>
#include <hip/hip_bf16.h>

typedef _Float16 f16;
typedef f16 f16x8 __attribute__((ext_vector_type(8)));
typedef f16 f16x4 __attribute__((ext_vector_type(4)));
typedef float f32x4 __attribute__((ext_vector_type(4)));
typedef int i32x4 __attribute__((ext_vector_type(4)));

#define MFMA16(a,b,c) __builtin_amdgcn_mfma_f32_16x16x32_f16(a,b,c,0,0,0)
#define BCAST(x) __builtin_bit_cast(f16x8, x)

// problem sizes
#define SS 128
#define HH 256
#define NSEQ 512

// workspace byte offsets (WS_NEED unchanged — proven to fit)
#define WS_E16   (0)
#define WS_W16   (33554432)
#define WS_SEN   (37224448)
#define WS_U1    (37748736)   // overlay during lstm0: hg[2][1024][256] f16 = exactly 1 MB
#define WS_H1    (38797312)   // overlay during lstm0: cnt[64] @128B stride (8 KB)
#define WS_LENS  (38813696)
#define WS_NEED  (38815744)
// lstm1 overlays in e16 region (dead after lstm0): hg2[2][16][256] @0 (16 KB), cnt2 @16384

// f16 weight pool element offsets
#define OFF_WIH0F 0
#define OFF_WHH0F 262144
#define OFF_WIH0B 524288
#define OFF_WHH0B 786432
#define OFF_WIH1  1048576
#define OFF_WHH1  1572864

__device__ __forceinline__ float fsig(float x){
  float e = __expf(-x);
  return __builtin_amdgcn_rcpf(1.f + e);
}
__device__ __forceinline__ float ftanh(float x){
  x = fminf(fmaxf(x, -15.f), 15.f);
  float e = __expf(2.f * x);
  return (e - 1.f) * __builtin_amdgcn_rcpf(e + 1.f);
}

// ---------------- fused weight f32 -> f16 convert ----------------
__global__ __launch_bounds__(256) void cvt_all_kernel(
    const float* __restrict__ a, const float* __restrict__ b,
    const float* __restrict__ c, const float* __restrict__ d,
    const float* __restrict__ e, const float* __restrict__ f,
    f16* __restrict__ dst){
  const int i = blockIdx.x * 256 + threadIdx.x;
  const float* s; int off;
  if      (i < 65536)  { s = a; off = i; }
  else if (i < 131072) { s = b; off = i - 65536; }
  else if (i < 196608) { s = c; off = i - 131072; }
  else if (i < 262144) { s = d; off = i - 196608; }
  else if (i < 393216) { s = e; off = i - 262144; }
  else                 { s = f; off = i - 393216; }
  const float4 v = *(const float4*)(s + (size_t)off * 4);
  f16x4 o; o[0] = (f16)v.x; o[1] = (f16)v.y; o[2] = (f16)v.z; o[3] = (f16)v.w;
  *(f16x4*)(dst + (size_t)i * 4) = o;
}

// ---------------- embedding gather -> e16[t][s][k] ----------------
__global__ __launch_bounds__(256) void gather_kernel(const int* __restrict__ x,
                                                     const float* __restrict__ emb,
                                                     f16* __restrict__ e16){
  const int tid = threadIdx.x;
  const int row = blockIdx.x * 4 + (tid >> 6);
  const int l = tid & 63;
  const int t = row >> 9, s = row & 511;
  const int token = x[s * SS + t];
  const float4 v = *(const float4*)(emb + (size_t)token * HH + l * 4);
  f16x4 o; o[0] = (f16)v.x; o[1] = (f16)v.y; o[2] = (f16)v.z; o[3] = (f16)v.w;
  *(f16x4*)(e16 + (size_t)row * HH + l * 4) = o;
}

// ---------------- sequence lengths ----------------
__global__ __launch_bounds__(64) void lens_kernel(const int* __restrict__ xm,
                                                  int* __restrict__ lens){
  const int s = blockIdx.x, l = threadIdx.x;
  const int v0 = (xm[s * SS + l] == 0) ? 1 : 0;
  const int v1 = (xm[s * SS + 64 + l] == 0) ? 1 : 0;
  unsigned long long b0 = __ballot(v0), b1 = __ballot(v1);
  if (l == 0) lens[s] = __popcll(b0) + __popcll(b1);
}

// ---------------- layer-0 bidirectional LSTM: quad-split, pinned register weights ----------------
// 256 WGs x 256 thr (4 waves, 1 wave/SIMD -> 512 VGPR budget). Group = 4 WGs
// (same XCD by bid%8 heuristic; protocol correct regardless). Member q owns
// 64 hidden channels; wave w owns 16. Weights (4g x 16j x 512K)/wave = 256
// VGPRs, asm-pinned. h exchanged via global double buffer + per-group counter:
// tid0 relaxed-spin + one acquire (L1/L2 inv), per-wave release-add (wbl2).
// h+e staged via LDS (stride 536: conflict-free) to cut post-inv refill traffic.
__global__ __launch_bounds__(256, 1) void lstm0_kernel(
    const f16* __restrict__ e16, const f16* __restrict__ w16,
    const float* __restrict__ b0f, const float* __restrict__ b0b,
    const int* __restrict__ lens, f16* __restrict__ hg,
    unsigned int* __restrict__ cnt, f16* __restrict__ sen16)
{
  __shared__ f16 sbuf[2][16][536];   // per row: h @0..255, e @268..523
  const int tid = threadIdx.x;
  const int w = tid >> 6, l = tid & 63;
  const int lrow = l & 15, lgrp = l >> 4;
  const int bid = blockIdx.x;
  const int xcd = bid & 7, slot = bid >> 3;
  const int grp = xcd * 8 + (slot >> 2);      // 0..63, members share xcd
  const int q = slot & 3;
  const int dir = grp >> 5, sbase = (grp & 31) * 16;
  const int dsbase = dir * 512 + sbase;
  const int jglob = q * 64 + w * 16 + lrow;

  const f16* __restrict__ Wih = w16 + (dir ? OFF_WIH0B : OFF_WIH0F);
  const f16* __restrict__ Whh = w16 + (dir ? OFF_WHH0B : OFF_WHH0F);
  const float* __restrict__ bias = dir ? b0b : b0f;

  // load + PIN weights: B[g][kk] kk<8 = Whh, kk>=8 = Wih
  i32x4 B[4][16];
  #pragma unroll
  for (int g = 0; g < 4; ++g){
    const int grow = g * 256 + jglob;
    const f16* ph = Whh + (size_t)grow * HH + lgrp * 8;
    const f16* pi = Wih + (size_t)grow * HH + lgrp * 8;
    #pragma unroll
    for (int kk = 0; kk < 8; ++kk){
      B[g][kk]     = *(const i32x4*)(ph + kk * 32);
      B[g][kk + 8] = *(const i32x4*)(pi + kk * 32);
    }
  }
  #pragma unroll
  for (int g = 0; g < 4; ++g)
    #pragma unroll
    for (int kk = 0; kk < 16; ++kk)
      asm volatile("" : "+v"(B[g][kk]));    // forbid rematerialization

  float bv[4];
  #pragma unroll
  for (int g = 0; g < 4; ++g) bv[g] = bias[g * 256 + jglob];
  int len4[4];
  #pragma unroll
  for (int r = 0; r < 4; ++r) len4[r] = lens[sbase + lgrp * 4 + r];

  const int srow = w * 4 + lgrp;    // staging row 0..15
  const int scol = l & 15;          // staging f16x8 slot
  float c4[4] = {}, h4[4] = {};
  unsigned int* cp = cnt + grp * 32;

  for (int tt = 0; tt < SS; ++tt){
    const int t = dir ? (SS - 1 - tt) : tt;
    const int cb = tt & 1, nb = cb ^ 1;

    // e: global->reg->LDS, before the spin (dbuf makes this race-free)
    const f16* esrc = e16 + ((size_t)(t * NSEQ + sbase + srow)) * HH;
    f16x8 ev0 = *(const f16x8*)(esrc + scol * 8);
    f16x8 ev1 = *(const f16x8*)(esrc + 128 + scol * 8);
    *(f16x8*)&sbuf[cb][srow][268 + scol * 8]       = ev0;
    *(f16x8*)&sbuf[cb][srow][268 + 128 + scol * 8] = ev1;

    if (tt > 0 && tid == 0){
      const unsigned int need = 16u * (unsigned)tt;
      while (__hip_atomic_load(cp, __ATOMIC_RELAXED, __HIP_MEMORY_SCOPE_AGENT) < need)
        __builtin_amdgcn_s_sleep(1);
      (void)__hip_atomic_load(cp, __ATOMIC_ACQUIRE, __HIP_MEMORY_SCOPE_AGENT); // inv L1/L2 once
    }
    __syncthreads();   // bar A

    // h: global->reg->LDS
    const f16* hsrc = hg + (size_t)cb * 262144 + (size_t)(dsbase + srow) * HH;
    f16x8 hv0 = *(const f16x8*)(hsrc + scol * 8);
    f16x8 hv1 = *(const f16x8*)(hsrc + 128 + scol * 8);
    *(f16x8*)&sbuf[cb][srow][scol * 8]       = hv0;
    *(f16x8*)&sbuf[cb][srow][128 + scol * 8] = hv1;
    __syncthreads();   // bar B

    f16x8 A[16];
    #pragma unroll
    for (int kk = 0; kk < 8; ++kk)
      A[kk] = *(const f16x8*)&sbuf[cb][lrow][kk * 32 + lgrp * 8];
    #pragma unroll
    for (int kk = 0; kk < 8; ++kk)
      A[kk + 8] = *(const f16x8*)&sbuf[cb][lrow][268 + kk * 32 + lgrp * 8];

    f32x4 ac[4];
    #pragma unroll
    for (int g = 0; g < 4; ++g){ ac[g][0]=0.f; ac[g][1]=0.f; ac[g][2]=0.f; ac[g][3]=0.f; }
    #pragma unroll
    for (int kk = 0; kk < 16; ++kk){
      ac[0] = MFMA16(A[kk], BCAST(B[0][kk]), ac[0]);
      ac[1] = MFMA16(A[kk], BCAST(B[1][kk]), ac[1]);
      ac[2] = MFMA16(A[kk], BCAST(B[2][kk]), ac[2]);
      ac[3] = MFMA16(A[kk], BCAST(B[3][kk]), ac[3]);
    }

    f16* hw = hg + (size_t)nb * 262144 + (size_t)(dsbase + lgrp * 4) * HH + jglob;
    #pragma unroll
    for (int r = 0; r < 4; ++r){
      const float iv = fsig (ac[0][r] + bv[0]);
      const float fv = fsig (ac[1][r] + bv[1]);
      const float gv = ftanh(ac[2][r] + bv[2]);
      const float ov = fsig (ac[3][r] + bv[3]);
      const float cn = fv * c4[r] + iv * gv;
      const float hn = ov * ftanh(cn);
      const bool vld = (t < len4[r]);
      c4[r] = vld ? cn : c4[r];
      h4[r] = vld ? hn : h4[r];
      hw[(size_t)r * HH] = (f16)h4[r];
    }
    if (l == 0)   // per-wave release: orders this wave's h-stores (wbl2)
      __hip_atomic_fetch_add(cp, 1u, __ATOMIC_RELEASE, __HIP_MEMORY_SCOPE_AGENT);
  }

  #pragma unroll
  for (int r = 0; r < 4; ++r){
    const int s = sbase + lgrp * 4 + r;
    sen16[(size_t)((s & 31) * 16 + (s >> 5)) * 512 + dir * 256 + jglob] = (f16)h4[r];
  }
}

// ---------------- layer-1 input GEMM: U1[p][gcol][b] ----------------
__global__ __launch_bounds__(256, 2) void u1_gemm_kernel(
    const f16* __restrict__ sen16, const f16* __restrict__ w16, f16* __restrict__ U1)
{
  const int tid = threadIdx.x;
  const int w = tid >> 6, l = tid & 63, lrow = l & 15, lgrp = l >> 4;
  const int p = blockIdx.x;
  const f16* __restrict__ Wih1 = w16 + OFF_WIH1;

  f16x8 A[16];
  #pragma unroll
  for (int kb = 0; kb < 16; ++kb)
    A[kb] = *(const f16x8*)&sen16[(size_t)(p * 16 + lrow) * 512 + kb * 32 + lgrp * 8];

  for (int tile = 0; tile < 16; ++tile){
    const int col = (w * 16 + tile) * 16 + lrow;
    const f16* wp = Wih1 + (size_t)col * 512 + lgrp * 8;
    f32x4 acc = {0.f,0.f,0.f,0.f};
    #pragma unroll
    for (int kb = 0; kb < 16; ++kb){
      f16x8 bfrag = *(const f16x8*)(wp + kb * 32);
      acc = MFMA16(A[kb], bfrag, acc);
    }
    f16x4 o4;
    #pragma unroll
    for (int r = 0; r < 4; ++r) o4[r] = (f16)acc[r];
    *(f16x4*)&U1[((size_t)p * 1024 + col) * 16 + lgrp * 4] = o4;
  }
}

// ---------------- layer-1 LSTM: 4-WG quad, pinned Whh1 ----------------
// grid 32 x 256thr; members at bid in {0,8,16,24} (same-XCD heuristic).
__global__ __launch_bounds__(256, 1) void lstm1_kernel(
    const f16* __restrict__ w16, const f16* __restrict__ U1,
    const float* __restrict__ b1, f16* __restrict__ hg2,
    unsigned int* __restrict__ cnt2, float* __restrict__ h1)
{
  const int bid = blockIdx.x;
  if (bid & 7) return;
  const int q = bid >> 3;
  const int tid = threadIdx.x;
  const int w = tid >> 6, l = tid & 63;
  const int lrow = l & 15, lgrp = l >> 4;
  const int jglob = q * 64 + w * 16 + lrow;
  const f16* __restrict__ Whh = w16 + OFF_WHH1;

  i32x4 B[4][8];
  #pragma unroll
  for (int g = 0; g < 4; ++g){
    const f16* ph = Whh + (size_t)(g * 256 + jglob) * HH + lgrp * 8;
    #pragma unroll
    for (int kk = 0; kk < 8; ++kk) B[g][kk] = *(const i32x4*)(ph + kk * 32);
  }
  #pragma unroll
  for (int g = 0; g < 4; ++g)
    #pragma unroll
    for (int kk = 0; kk < 8; ++kk)
      asm volatile("" : "+v"(B[g][kk]));

  float bv[4];
  #pragma unroll
  for (int g = 0; g < 4; ++g) bv[g] = b1[g * 256 + jglob];
  float c4[4] = {}, h4[4] = {};

  for (int pt = 0; pt < 32; ++pt){
    const int cb = pt & 1, nb = cb ^ 1;
    if (pt > 0 && tid == 0){
      const unsigned int need = 16u * (unsigned)pt;
      while (__hip_atomic_load(cnt2, __ATOMIC_RELAXED, __HIP_MEMORY_SCOPE_AGENT) < need)
        __builtin_amdgcn_s_sleep(1);
      (void)__hip_atomic_load(cnt2, __ATOMIC_ACQUIRE, __HIP_MEMORY_SCOPE_AGENT);
    }
    __syncthreads();

    f16x8 A[8];
    const f16* hp = hg2 + (size_t)cb * 4096 + (size_t)lrow * HH + lgrp * 8;
    #pragma unroll
    for (int kk = 0; kk < 8; ++kk) A[kk] = *(const f16x8*)(hp + kk * 32);

    f32x4 ac[4];
    #pragma unroll
    for (int g = 0; g < 4; ++g){ ac[g][0]=0.f; ac[g][1]=0.f; ac[g][2]=0.f; ac[g][3]=0.f; }
    #pragma unroll
    for (int kk = 0; kk < 8; ++kk){
      ac[0] = MFMA16(A[kk], BCAST(B[0][kk]), ac[0]);
      ac[1] = MFMA16(A[kk], BCAST(B[1][kk]), ac[1]);
      ac[2] = MFMA16(A[kk], BCAST(B[2][kk]), ac[2]);
      ac[3] = MFMA16(A[kk], BCAST(B[3][kk]), ac[3]);
    }

    f16x4 u[4];
    #pragma unroll
    for (int g = 0; g < 4; ++g)
      u[g] = *(const f16x4*)&U1[((size_t)pt * 1024 + g * 256 + jglob) * 16 + lgrp * 4];

    f16* hw = hg2 + (size_t)nb * 4096 + (size_t)(lgrp * 4) * HH + jglob;
    #pragma unroll
    for (int r = 0; r < 4; ++r){
      const float iv = fsig (ac[0][r] + (float)u[0][r] + bv[0]);
      const float fv = fsig (ac[1][r] + (float)u[1][r] + bv[1]);
      const float gv = ftanh(ac[2][r] + (float)u[2][r] + bv[2]);
      const float ov = fsig (ac[3][r] + (float)u[3][r] + bv[3]);
      const float cn = fv * c4[r] + iv * gv;
      c4[r] = cn;
      h4[r] = ov * ftanh(cn);
      hw[(size_t)r * HH] = (f16)h4[r];
    }
    if (l == 0)
      __hip_atomic_fetch_add(cnt2, 1u, __ATOMIC_RELEASE, __HIP_MEMORY_SCOPE_AGENT);
  }

  #pragma unroll
  for (int r = 0; r < 4; ++r)
    h1[(lgrp * 4 + r) * 256 + jglob] = h4[r];
}

// ---------------- final FC ----------------
__global__ __launch_bounds__(256) void fc_kernel(const float* __restrict__ h1,
                                                 const float* __restrict__ Wfc,
                                                 const float* __restrict__ bfc,
                                                 float* __restrict__ out){
  __shared__ float hl[16 * 256];
  const int tid = threadIdx.x;
  for (int i = tid; i < 4096; i += 256) hl[i] = h1[i];
  __syncthreads();
  const int o = tid & 127, half = tid >> 7;
  float acc[8];
  #pragma unroll
  for (int i = 0; i < 8; ++i) acc[i] = bfc[o];
  const float* wp = Wfc + (size_t)o * 256;
  for (int j = 0; j < 256; ++j){
    const float wv = wp[j];
    #pragma unroll
    for (int i = 0; i < 8; ++i) acc[i] += wv * hl[(half * 8 + i) * 256 + j];
  }
  #pragma unroll
  for (int i = 0; i < 8; ++i) out[(half * 8 + i) * 128 + o] = acc[i];
}

extern "C" void kernel_launch(void* const* d_in, const int* in_sizes, int n_in,
                              void* d_out, int out_size, void* d_ws, size_t ws_size,
                              hipStream_t stream) {
  if (ws_size < (size_t)WS_NEED) return;

  const int*   x     = (const int*)  d_in[0];
  const int*   xm    = (const int*)  d_in[1];
  const float* emb   = (const float*)d_in[2];
  const float* Wih0f = (const float*)d_in[3];
  const float* Whh0f = (const float*)d_in[4];
  const float* b0f   = (const float*)d_in[5];
  const float* Wih0b = (const float*)d_in[6];
  const float* Whh0b = (const float*)d_in[7];
  const float* b0b   = (const float*)d_in[8];
  const float* Wih1  = (const float*)d_in[9];
  const float* Whh1  = (const float*)d_in[10];
  const float* b1    = (const float*)d_in[11];
  const float* Wfc   = (const float*)d_in[12];
  const float* bfc   = (const float*)d_in[13];
  float* out = (float*)d_out;
  char*  ws  = (char*)d_ws;

  f16*   e16   = (f16*)(ws + WS_E16);
  f16*   w16   = (f16*)(ws + WS_W16);
  f16*   sen16 = (f16*)(ws + WS_SEN);
  f16*   U1    = (f16*)(ws + WS_U1);
  float* h1    = (float*)(ws + WS_H1);
  int*   lens  = (int*)(ws + WS_LENS);
  // lstm0 overlays (dead before u1_gemm/lstm1)
  f16*          hg0  = (f16*)(ws + WS_U1);
  unsigned int* cnt0 = (unsigned int*)(ws + WS_H1);
  // lstm1 overlays (e16 region, dead after lstm0)
  f16*          hg2  = (f16*)(ws + 0);
  unsigned int* cnt2 = (unsigned int*)(ws + 16384);

  cvt_all_kernel<<<1792, 256, 0, stream>>>(Wih0f, Whh0f, Wih0b, Whh0b, Wih1, Whh1, w16);
  gather_kernel<<<16384, 256, 0, stream>>>(x, emb, e16);
  lens_kernel<<<512, 64, 0, stream>>>(xm, lens);

  hipMemsetAsync(ws + WS_U1, 0, 524288, stream);   // hg buf0 = h(0) = 0
  hipMemsetAsync(ws + WS_H1, 0, 8192, stream);     // cnt0[64] = 0
  lstm0_kernel<<<256, 256, 0, stream>>>(e16, w16, b0f, b0b, lens, hg0, cnt0, sen16);

  hipMemsetAsync(ws + 0, 0, 16512, stream);        // hg2 (both bufs) + cnt2 = 0
  u1_gemm_kernel<<<32, 256, 0, stream>>>(sen16, w16, U1);
  lstm1_kernel<<<32, 256, 0, stream>>>(w16, U1, b1, hg2, cnt2, h1);
  fc_kernel<<<1, 256, 0, stream>>>(h1, Wfc, bfc, out);
}

// Round 9
// 832.884 us; speedup vs baseline: 6.9030x; 3.2152x over previous
//
#include <hip/hip_runtime.h>
#include <hip/hip_bf16.h>

typedef _Float16 f16;
typedef f16 f16x8 __attribute__((ext_vector_type(8)));
typedef f16 f16x4 __attribute__((ext_vector_type(4)));
typedef float f32x4 __attribute__((ext_vector_type(4)));
typedef int i32x4 __attribute__((ext_vector_type(4)));
typedef unsigned long long ull;

#define MFMA16(a,b,c) __builtin_amdgcn_mfma_f32_16x16x32_f16(a,b,c,0,0,0)
#define BCAST(x) __builtin_bit_cast(f16x8, x)

// problem sizes
#define SS 128
#define HH 256
#define NSEQ 512

// workspace byte offsets
#define WS_E16   (0)
#define WS_W16   (33554432)
#define WS_SEN   (37224448)
#define WS_U1    (37748736)   // overlay during lstm0: hg[2][1024][256] f16 = 1 MB
#define WS_H1    (38797312)   // overlay during lstm0: cnt[64] @128B stride
#define WS_LENS  (38813696)
#define WS_NEED  (38815744)
// lstm1 overlays in e16 region: hg2[2][16][256] @0, cnt2 @16384

// f16 weight pool element offsets
#define OFF_WIH0F 0
#define OFF_WHH0F 262144
#define OFF_WIH0B 524288
#define OFF_WHH0B 786432
#define OFF_WIH1  1048576
#define OFF_WHH1  1572864

__device__ __forceinline__ float fsig(float x){
  float e = __expf(-x);
  return __builtin_amdgcn_rcpf(1.f + e);
}
__device__ __forceinline__ float ftanh(float x){
  x = fminf(fmaxf(x, -15.f), 15.f);
  float e = __expf(2.f * x);
  return (e - 1.f) * __builtin_amdgcn_rcpf(e + 1.f);
}

// 16B fragment read as two 8B agent-relaxed atomic loads (sc1: coherent at MALL,
// bypasses possibly-stale local L2; NO cache maintenance emitted).
__device__ __forceinline__ f16x8 ld_h8(const f16* p){
  union { ull u[2]; f16x8 v; } x;
  x.u[0] = __hip_atomic_load((const ull*)p,       __ATOMIC_RELAXED, __HIP_MEMORY_SCOPE_AGENT);
  x.u[1] = __hip_atomic_load((const ull*)(p + 4), __ATOMIC_RELAXED, __HIP_MEMORY_SCOPE_AGENT);
  return x.v;
}
__device__ __forceinline__ void st_h8b(f16* p, ull v){
  __hip_atomic_store((ull*)p, v, __ATOMIC_RELAXED, __HIP_MEMORY_SCOPE_AGENT);
}

// ---------------- fused weight f32 -> f16 convert ----------------
__global__ __launch_bounds__(256) void cvt_all_kernel(
    const float* __restrict__ a, const float* __restrict__ b,
    const float* __restrict__ c, const float* __restrict__ d,
    const float* __restrict__ e, const float* __restrict__ f,
    f16* __restrict__ dst){
  const int i = blockIdx.x * 256 + threadIdx.x;
  const float* s; int off;
  if      (i < 65536)  { s = a; off = i; }
  else if (i < 131072) { s = b; off = i - 65536; }
  else if (i < 196608) { s = c; off = i - 131072; }
  else if (i < 262144) { s = d; off = i - 196608; }
  else if (i < 393216) { s = e; off = i - 262144; }
  else                 { s = f; off = i - 393216; }
  const float4 v = *(const float4*)(s + (size_t)off * 4);
  f16x4 o; o[0] = (f16)v.x; o[1] = (f16)v.y; o[2] = (f16)v.z; o[3] = (f16)v.w;
  *(f16x4*)(dst + (size_t)i * 4) = o;
}

// ---------------- embedding gather -> e16[t][s][k] ----------------
__global__ __launch_bounds__(256) void gather_kernel(const int* __restrict__ x,
                                                     const float* __restrict__ emb,
                                                     f16* __restrict__ e16){
  const int tid = threadIdx.x;
  const int row = blockIdx.x * 4 + (tid >> 6);
  const int l = tid & 63;
  const int t = row >> 9, s = row & 511;
  const int token = x[s * SS + t];
  const float4 v = *(const float4*)(emb + (size_t)token * HH + l * 4);
  f16x4 o; o[0] = (f16)v.x; o[1] = (f16)v.y; o[2] = (f16)v.z; o[3] = (f16)v.w;
  *(f16x4*)(e16 + (size_t)row * HH + l * 4) = o;
}

// ---------------- sequence lengths ----------------
__global__ __launch_bounds__(64) void lens_kernel(const int* __restrict__ xm,
                                                  int* __restrict__ lens){
  const int s = blockIdx.x, l = threadIdx.x;
  const int v0 = (xm[s * SS + l] == 0) ? 1 : 0;
  const int v1 = (xm[s * SS + 64 + l] == 0) ? 1 : 0;
  unsigned long long b0 = __ballot(v0), b1 = __ballot(v1);
  if (l == 0) lens[s] = __popcll(b0) + __popcll(b1);
}

// ---------------- layer-0 bidirectional LSTM: quad-split + MALL-coherent exchange ----------------
// 256 WGs x 256 thr, group = 4 WGs. Weights pinned in registers (proven r8:
// FETCH=38MB). h exchange: LDS transpose -> 8B agent-relaxed atomic stores
// (write-through to MALL) -> syncthreads (drains vmcnt) -> relaxed +1/WG.
// Reader: tid0 relaxed-poll cnt>=4*tt, lanes ld_h8 (sc1, bypass stale L2).
// NO release/acquire -> NO wbl2/inv storms (r8 lesson: those cost 18us/step).
__global__ __launch_bounds__(256, 1) void lstm0_kernel(
    const f16* __restrict__ e16, const f16* __restrict__ w16,
    const float* __restrict__ b0f, const float* __restrict__ b0b,
    const int* __restrict__ lens, f16* __restrict__ hg,
    unsigned int* __restrict__ cnt, f16* __restrict__ sen16)
{
  __shared__ f16 sbuf[16][72];   // outgoing h transpose stage (j-local 0..63)
  const int tid = threadIdx.x;
  const int w = tid >> 6, l = tid & 63;
  const int lrow = l & 15, lgrp = l >> 4;
  const int bid = blockIdx.x;
  const int xcd = bid & 7, slot = bid >> 3;
  const int grp = xcd * 8 + (slot >> 2);
  const int q = slot & 3;
  const int dir = grp >> 5, sbase = (grp & 31) * 16;
  const int dsbase = dir * 512 + sbase;
  const int jglob = q * 64 + w * 16 + lrow;

  const f16* __restrict__ Wih = w16 + (dir ? OFF_WIH0B : OFF_WIH0F);
  const f16* __restrict__ Whh = w16 + (dir ? OFF_WHH0B : OFF_WHH0F);
  const float* __restrict__ bias = dir ? b0b : b0f;

  // load + PIN weights: B[g][kk] kk<8 = Whh, kk>=8 = Wih
  i32x4 B[4][16];
  #pragma unroll
  for (int g = 0; g < 4; ++g){
    const int grow = g * 256 + jglob;
    const f16* ph = Whh + (size_t)grow * HH + lgrp * 8;
    const f16* pi = Wih + (size_t)grow * HH + lgrp * 8;
    #pragma unroll
    for (int kk = 0; kk < 8; ++kk){
      B[g][kk]     = *(const i32x4*)(ph + kk * 32);
      B[g][kk + 8] = *(const i32x4*)(pi + kk * 32);
    }
  }
  #pragma unroll
  for (int g = 0; g < 4; ++g)
    #pragma unroll
    for (int kk = 0; kk < 16; ++kk)
      asm volatile("" : "+v"(B[g][kk]));    // forbid rematerialization

  float bv[4];
  #pragma unroll
  for (int g = 0; g < 4; ++g) bv[g] = bias[g * 256 + jglob];
  int len4[4];
  #pragma unroll
  for (int r = 0; r < 4; ++r) len4[r] = lens[sbase + lgrp * 4 + r];

  float c4[4] = {}, h4[4] = {};
  unsigned int* cp = cnt + grp * 32;
  const int srow = tid >> 4, part = tid & 15;   // out-stage assignment

  for (int tt = 0; tt < SS; ++tt){
    const int t = dir ? (SS - 1 - tt) : tt;
    const int cb = tt & 1, nb = cb ^ 1;

    f16x8 A[16];
    // e-part: normal cached loads, issued before the poll to hide L2 latency
    const f16* ep = e16 + ((size_t)(t * NSEQ + sbase + lrow)) * HH + lgrp * 8;
    #pragma unroll
    for (int kk = 0; kk < 8; ++kk) A[kk + 8] = *(const f16x8*)(ep + kk * 32);

    if (tt > 0){
      if (tid == 0){
        const unsigned int need = 4u * (unsigned)tt;
        while (__hip_atomic_load(cp, __ATOMIC_RELAXED, __HIP_MEMORY_SCOPE_AGENT) < need)
          __builtin_amdgcn_s_sleep(1);
      }
      __syncthreads();
    }

    // h-part: coherent loads from MALL (fresh by construction: peers' stores
    // were vmcnt-drained before their counter add)
    const f16* hrow = hg + ((size_t)cb * 1024 + dsbase + lrow) * HH + lgrp * 8;
    #pragma unroll
    for (int kk = 0; kk < 8; ++kk) A[kk] = ld_h8(hrow + kk * 32);

    f32x4 ac[4];
    #pragma unroll
    for (int g = 0; g < 4; ++g){ ac[g][0]=0.f; ac[g][1]=0.f; ac[g][2]=0.f; ac[g][3]=0.f; }
    #pragma unroll
    for (int kk = 0; kk < 16; ++kk){
      ac[0] = MFMA16(A[kk], BCAST(B[0][kk]), ac[0]);
      ac[1] = MFMA16(A[kk], BCAST(B[1][kk]), ac[1]);
      ac[2] = MFMA16(A[kk], BCAST(B[2][kk]), ac[2]);
      ac[3] = MFMA16(A[kk], BCAST(B[3][kk]), ac[3]);
    }

    #pragma unroll
    for (int r = 0; r < 4; ++r){
      const float iv = fsig (ac[0][r] + bv[0]);
      const float fv = fsig (ac[1][r] + bv[1]);
      const float gv = ftanh(ac[2][r] + bv[2]);
      const float ov = fsig (ac[3][r] + bv[3]);
      const float cn = fv * c4[r] + iv * gv;
      const float hn = ov * ftanh(cn);
      const bool vld = (t < len4[r]);
      c4[r] = vld ? cn : c4[r];
      h4[r] = vld ? hn : h4[r];
      sbuf[lgrp * 4 + r][w * 16 + lrow] = (f16)h4[r];   // transpose stage
    }
    __syncthreads();   // sbuf ready (also closes prev read phase)

    // out: one 8B coherent store per thread, [s][j]-contiguous
    const ull ov = *(const ull*)&sbuf[srow][part * 4];
    st_h8b(hg + ((size_t)nb * 1024 + dsbase + srow) * HH + q * 64 + part * 4, ov);
    __syncthreads();   // compiler drains vmcnt(0) here -> stores at MALL
    if (tid == 0)
      __hip_atomic_fetch_add(cp, 1u, __ATOMIC_RELAXED, __HIP_MEMORY_SCOPE_AGENT);
  }

  #pragma unroll
  for (int r = 0; r < 4; ++r){
    const int s = sbase + lgrp * 4 + r;
    sen16[(size_t)((s & 31) * 16 + (s >> 5)) * 512 + dir * 256 + jglob] = (f16)h4[r];
  }
}

// ---------------- layer-1 input GEMM: U1[p][gcol][b] ----------------
__global__ __launch_bounds__(256, 2) void u1_gemm_kernel(
    const f16* __restrict__ sen16, const f16* __restrict__ w16, f16* __restrict__ U1)
{
  const int tid = threadIdx.x;
  const int w = tid >> 6, l = tid & 63, lrow = l & 15, lgrp = l >> 4;
  const int p = blockIdx.x;
  const f16* __restrict__ Wih1 = w16 + OFF_WIH1;

  f16x8 A[16];
  #pragma unroll
  for (int kb = 0; kb < 16; ++kb)
    A[kb] = *(const f16x8*)&sen16[(size_t)(p * 16 + lrow) * 512 + kb * 32 + lgrp * 8];

  for (int tile = 0; tile < 16; ++tile){
    const int col = (w * 16 + tile) * 16 + lrow;
    const f16* wp = Wih1 + (size_t)col * 512 + lgrp * 8;
    f32x4 acc = {0.f,0.f,0.f,0.f};
    #pragma unroll
    for (int kb = 0; kb < 16; ++kb){
      f16x8 bfrag = *(const f16x8*)(wp + kb * 32);
      acc = MFMA16(A[kb], bfrag, acc);
    }
    f16x4 o4;
    #pragma unroll
    for (int r = 0; r < 4; ++r) o4[r] = (f16)acc[r];
    *(f16x4*)&U1[((size_t)p * 1024 + col) * 16 + lgrp * 4] = o4;
  }
}

// ---------------- layer-1 LSTM: 4-WG quad, same MALL-coherent protocol ----------------
__global__ __launch_bounds__(256, 1) void lstm1_kernel(
    const f16* __restrict__ w16, const f16* __restrict__ U1,
    const float* __restrict__ b1, f16* __restrict__ hg2,
    unsigned int* __restrict__ cnt2, float* __restrict__ h1)
{
  const int bid = blockIdx.x;
  if (bid & 7) return;
  __shared__ f16 sbuf[16][72];
  const int q = bid >> 3;
  const int tid = threadIdx.x;
  const int w = tid >> 6, l = tid & 63;
  const int lrow = l & 15, lgrp = l >> 4;
  const int jglob = q * 64 + w * 16 + lrow;
  const f16* __restrict__ Whh = w16 + OFF_WHH1;

  i32x4 B[4][8];
  #pragma unroll
  for (int g = 0; g < 4; ++g){
    const f16* ph = Whh + (size_t)(g * 256 + jglob) * HH + lgrp * 8;
    #pragma unroll
    for (int kk = 0; kk < 8; ++kk) B[g][kk] = *(const i32x4*)(ph + kk * 32);
  }
  #pragma unroll
  for (int g = 0; g < 4; ++g)
    #pragma unroll
    for (int kk = 0; kk < 8; ++kk)
      asm volatile("" : "+v"(B[g][kk]));

  float bv[4];
  #pragma unroll
  for (int g = 0; g < 4; ++g) bv[g] = b1[g * 256 + jglob];
  float c4[4] = {}, h4[4] = {};
  const int srow = tid >> 4, part = tid & 15;

  for (int pt = 0; pt < 32; ++pt){
    const int cb = pt & 1, nb = cb ^ 1;

    f16x4 u[4];
    #pragma unroll
    for (int g = 0; g < 4; ++g)
      u[g] = *(const f16x4*)&U1[((size_t)pt * 1024 + g * 256 + jglob) * 16 + lgrp * 4];

    if (pt > 0){
      if (tid == 0){
        const unsigned int need = 4u * (unsigned)pt;
        while (__hip_atomic_load(cnt2, __ATOMIC_RELAXED, __HIP_MEMORY_SCOPE_AGENT) < need)
          __builtin_amdgcn_s_sleep(1);
      }
      __syncthreads();
    }

    f16x8 A[8];
    const f16* hrow = hg2 + ((size_t)cb * 16 + lrow) * HH + lgrp * 8;
    #pragma unroll
    for (int kk = 0; kk < 8; ++kk) A[kk] = ld_h8(hrow + kk * 32);

    f32x4 ac[4];
    #pragma unroll
    for (int g = 0; g < 4; ++g){ ac[g][0]=0.f; ac[g][1]=0.f; ac[g][2]=0.f; ac[g][3]=0.f; }
    #pragma unroll
    for (int kk = 0; kk < 8; ++kk){
      ac[0] = MFMA16(A[kk], BCAST(B[0][kk]), ac[0]);
      ac[1] = MFMA16(A[kk], BCAST(B[1][kk]), ac[1]);
      ac[2] = MFMA16(A[kk], BCAST(B[2][kk]), ac[2]);
      ac[3] = MFMA16(A[kk], BCAST(B[3][kk]), ac[3]);
    }

    #pragma unroll
    for (int r = 0; r < 4; ++r){
      const float iv = fsig (ac[0][r] + (float)u[0][r] + bv[0]);
      const float fv = fsig (ac[1][r] + (float)u[1][r] + bv[1]);
      const float gv = ftanh(ac[2][r] + (float)u[2][r] + bv[2]);
      const float ov = fsig (ac[3][r] + (float)u[3][r] + bv[3]);
      const float cn = fv * c4[r] + iv * gv;
      c4[r] = cn;
      h4[r] = ov * ftanh(cn);
      sbuf[lgrp * 4 + r][w * 16 + lrow] = (f16)h4[r];
    }
    __syncthreads();

    const ull ov = *(const ull*)&sbuf[srow][part * 4];
    st_h8b(hg2 + ((size_t)nb * 16 + srow) * HH + q * 64 + part * 4, ov);
    __syncthreads();
    if (tid == 0)
      __hip_atomic_fetch_add(cnt2, 1u, __ATOMIC_RELAXED, __HIP_MEMORY_SCOPE_AGENT);
  }

  #pragma unroll
  for (int r = 0; r < 4; ++r)
    h1[(lgrp * 4 + r) * 256 + jglob] = h4[r];
}

// ---------------- final FC ----------------
__global__ __launch_bounds__(256) void fc_kernel(const float* __restrict__ h1,
                                                 const float* __restrict__ Wfc,
                                                 const float* __restrict__ bfc,
                                                 float* __restrict__ out){
  __shared__ float hl[16 * 256];
  const int tid = threadIdx.x;
  for (int i = tid; i < 4096; i += 256) hl[i] = h1[i];
  __syncthreads();
  const int o = tid & 127, half = tid >> 7;
  float acc[8];
  #pragma unroll
  for (int i = 0; i < 8; ++i) acc[i] = bfc[o];
  const float* wp = Wfc + (size_t)o * 256;
  for (int j = 0; j < 256; ++j){
    const float wv = wp[j];
    #pragma unroll
    for (int i = 0; i < 8; ++i) acc[i] += wv * hl[(half * 8 + i) * 256 + j];
  }
  #pragma unroll
  for (int i = 0; i < 8; ++i) out[(half * 8 + i) * 128 + o] = acc[i];
}

extern "C" void kernel_launch(void* const* d_in, const int* in_sizes, int n_in,
                              void* d_out, int out_size, void* d_ws, size_t ws_size,
                              hipStream_t stream) {
  if (ws_size < (size_t)WS_NEED) return;

  const int*   x     = (const int*)  d_in[0];
  const int*   xm    = (const int*)  d_in[1];
  const float* emb   = (const float*)d_in[2];
  const float* Wih0f = (const float*)d_in[3];
  const float* Whh0f = (const float*)d_in[4];
  const float* b0f   = (const float*)d_in[5];
  const float* Wih0b = (const float*)d_in[6];
  const float* Whh0b = (const float*)d_in[7];
  const float* b0b   = (const float*)d_in[8];
  const float* Wih1  = (const float*)d_in[9];
  const float* Whh1  = (const float*)d_in[10];
  const float* b1    = (const float*)d_in[11];
  const float* Wfc   = (const float*)d_in[12];
  const float* bfc   = (const float*)d_in[13];
  float* out = (float*)d_out;
  char*  ws  = (char*)d_ws;

  f16*   e16   = (f16*)(ws + WS_E16);
  f16*   w16   = (f16*)(ws + WS_W16);
  f16*   sen16 = (f16*)(ws + WS_SEN);
  f16*   U1    = (f16*)(ws + WS_U1);
  float* h1    = (float*)(ws + WS_H1);
  int*   lens  = (int*)(ws + WS_LENS);
  // lstm0 overlays (dead before u1_gemm/lstm1)
  f16*          hg0  = (f16*)(ws + WS_U1);
  unsigned int* cnt0 = (unsigned int*)(ws + WS_H1);
  // lstm1 overlays (e16 region, dead after lstm0)
  f16*          hg2  = (f16*)(ws + 0);
  unsigned int* cnt2 = (unsigned int*)(ws + 16384);

  cvt_all_kernel<<<1792, 256, 0, stream>>>(Wih0f, Whh0f, Wih0b, Whh0b, Wih1, Whh1, w16);
  gather_kernel<<<16384, 256, 0, stream>>>(x, emb, e16);
  lens_kernel<<<512, 64, 0, stream>>>(xm, lens);

  hipMemsetAsync(ws + WS_U1, 0, 524288, stream);   // hg buf0 = h(0) = 0
  hipMemsetAsync(ws + WS_H1, 0, 8192, stream);     // cnt0[64] = 0
  lstm0_kernel<<<256, 256, 0, stream>>>(e16, w16, b0f, b0b, lens, hg0, cnt0, sen16);

  hipMemsetAsync(ws + 0, 0, 16512, stream);        // hg2 (both bufs) + cnt2 = 0
  u1_gemm_kernel<<<32, 256, 0, stream>>>(sen16, w16, U1);
  lstm1_kernel<<<32, 256, 0, stream>>>(w16, U1, b1, hg2, cnt2, h1);
  fc_kernel<<<1, 256, 0, stream>>>(h1, Wfc, bfc, out);
}

// Round 10
// 813.408 us; speedup vs baseline: 7.0683x; 1.0239x over previous
//
#include <hip/hip_runtime.h>
#include <hip/hip_bf16.h>

typedef _Float16 f16;
typedef f16 f16x8 __attribute__((ext_vector_type(8)));
typedef f16 f16x4 __attribute__((ext_vector_type(4)));
typedef float f32x4 __attribute__((ext_vector_type(4)));
typedef int i32x4 __attribute__((ext_vector_type(4)));
typedef unsigned long long ull;
typedef unsigned short u16;

#define MFMA16(a,b,c) __builtin_amdgcn_mfma_f32_16x16x32_f16(a,b,c,0,0,0)
#define BCAST(x) __builtin_bit_cast(f16x8, x)

// problem sizes
#define SS 128
#define HH 256
#define NSEQ 512

// ws layout (WS_NEED unchanged vs r4-r9; tag buffers live in the freed e16 region)
#define WS_TAGS0 (0)         // [grp64][slot2][row16][quar4][word22] x8B = 1441792
#define WS_TAGS1 (1572864)   // [slot2][row16][half2][word43] x8B = 22016
#define WS_W16   (33554432)
#define WS_SEN   (37224448)
#define WS_U1    (37748736)
#define WS_H1    (38797312)
#define WS_LENS  (38813696)
#define WS_NEED  (38815744)

// f16 weight pool element offsets
#define OFF_WIH0F 0
#define OFF_WHH0F 262144
#define OFF_WIH0B 524288
#define OFF_WHH0B 786432
#define OFF_WIH1  1048576
#define OFF_WHH1  1572864

__device__ __forceinline__ float fsig(float x){
  float e = __expf(-x);
  return __builtin_amdgcn_rcpf(1.f + e);
}
__device__ __forceinline__ float ftanh(float x){
  x = fminf(fmaxf(x, -15.f), 15.f);
  float e = __expf(2.f * x);
  return (e - 1.f) * __builtin_amdgcn_rcpf(e + 1.f);
}

// ---------------- fused weight f32 -> f16 convert ----------------
__global__ __launch_bounds__(256) void cvt_all_kernel(
    const float* __restrict__ a, const float* __restrict__ b,
    const float* __restrict__ c, const float* __restrict__ d,
    const float* __restrict__ e, const float* __restrict__ f,
    f16* __restrict__ dst){
  const int i = blockIdx.x * 256 + threadIdx.x;
  const float* s; int off;
  if      (i < 65536)  { s = a; off = i; }
  else if (i < 131072) { s = b; off = i - 65536; }
  else if (i < 196608) { s = c; off = i - 131072; }
  else if (i < 262144) { s = d; off = i - 196608; }
  else if (i < 393216) { s = e; off = i - 262144; }
  else                 { s = f; off = i - 393216; }
  const float4 v = *(const float4*)(s + (size_t)off * 4);
  f16x4 o; o[0] = (f16)v.x; o[1] = (f16)v.y; o[2] = (f16)v.z; o[3] = (f16)v.w;
  *(f16x4*)(dst + (size_t)i * 4) = o;
}

// ---------------- sequence lengths ----------------
__global__ __launch_bounds__(64) void lens_kernel(const int* __restrict__ xm,
                                                  int* __restrict__ lens){
  const int s = blockIdx.x, l = threadIdx.x;
  const int v0 = (xm[s * SS + l] == 0) ? 1 : 0;
  const int v1 = (xm[s * SS + 64 + l] == 0) ? 1 : 0;
  unsigned long long b0 = __ballot(v0), b1 = __ballot(v1);
  if (l == 0) lens[s] = __popcll(b0) + __popcll(b1);
}

// ---------------- layer-0 bidirectional LSTM ----------------
// 256 WGs x 256 thr, quad groups (4 WGs, j-quarters), weights pinned in VGPRs
// (proven r8/r9). Embedding gather FUSED (token ids in LDS, emb rows read f32).
// h exchange: single-leg tagged words — 8B = [3x f16 | u16 step tag] stored with
// ONE relaxed agent atomic (single-copy atomic => tag valid <=> payload valid).
// Consumer polls the words themselves; 2 slots (consume-before-produce chain
// makes slot reuse safe). No counters, no release/acquire, no cache maintenance.
__global__ __launch_bounds__(256, 1) void lstm0_kernel(
    const int* __restrict__ x, const float* __restrict__ emb,
    const f16* __restrict__ w16,
    const float* __restrict__ b0f, const float* __restrict__ b0b,
    const int* __restrict__ lens, char* __restrict__ tags,
    f16* __restrict__ sen16)
{
  __shared__ f16 himg[2][16][264];   // full 256-j h image per parity
  __shared__ int xlds[16][128];      // token ids for this group's 16 seqs
  const int tid = threadIdx.x;
  const int w = tid >> 6, l = tid & 63;
  const int lrow = l & 15, lgrp = l >> 4;
  const int bid = blockIdx.x;
  const int xcd = bid & 7, slot8 = bid >> 3;
  const int grp = xcd * 8 + (slot8 >> 2);    // 0..63
  const int q = slot8 & 3;                   // j-quarter owned by this WG
  const int dir = grp >> 5, sbase = (grp & 31) * 16;
  const int jglob = q * 64 + w * 16 + lrow;

  const f16* __restrict__ Wih = w16 + (dir ? OFF_WIH0B : OFF_WIH0F);
  const f16* __restrict__ Whh = w16 + (dir ? OFF_WHH0B : OFF_WHH0F);
  const float* __restrict__ bias = dir ? b0b : b0f;

  // load + PIN weights: B[g][kk] kk<8 = Whh, kk>=8 = Wih
  i32x4 B[4][16];
  #pragma unroll
  for (int g = 0; g < 4; ++g){
    const int grow = g * 256 + jglob;
    const f16* ph = Whh + (size_t)grow * HH + lgrp * 8;
    const f16* pi = Wih + (size_t)grow * HH + lgrp * 8;
    #pragma unroll
    for (int kk = 0; kk < 8; ++kk){
      B[g][kk]     = *(const i32x4*)(ph + kk * 32);
      B[g][kk + 8] = *(const i32x4*)(pi + kk * 32);
    }
  }
  #pragma unroll
  for (int g = 0; g < 4; ++g)
    #pragma unroll
    for (int kk = 0; kk < 16; ++kk)
      asm volatile("" : "+v"(B[g][kk]));    // forbid rematerialization

  float bv[4];
  #pragma unroll
  for (int g = 0; g < 4; ++g) bv[g] = bias[g * 256 + jglob];
  int len4[4];
  #pragma unroll
  for (int r = 0; r < 4; ++r) len4[r] = lens[sbase + lgrp * 4 + r];

  for (int i = tid; i < 2 * 16 * 264; i += 256) ((f16*)himg)[i] = (f16)0.f;
  for (int i = tid; i < 2048; i += 256)
    ((int*)xlds)[i] = x[(sbase + (i >> 7)) * SS + (i & 127)];
  __syncthreads();

  // consumer units: 3 remote quarters x 16 rows x 22 words = 1056
  const int nu = (tid < 32) ? 5 : 4;
  int uoff[5], urow[5], uj0[5], ujb[5];
  #pragma unroll
  for (int i = 0; i < 5; ++i){
    int u = tid + (i << 8); if (u > 1055) u = 1055;
    const int qi = u / 352;
    const int rem = u - qi * 352;
    const int r = rem / 22;
    const int wd = rem - r * 22;
    const int qa = qi + (qi >= q ? 1 : 0);   // skip own quarter
    uoff[i] = ((((r << 2) + qa) * 22 + wd) << 3);
    urow[i] = r; ujb[i] = wd * 3; uj0[i] = (qa << 6) + wd * 3;
  }
  const int prow = tid >> 4, pw = tid & 15;
  char* const gbase = tags + (size_t)grp * 22528;

  float c4[4] = {}, h4[4] = {};

  for (int tt = 0; tt < SS; ++tt){
    const int t = dir ? (SS - 1 - tt) : tt;
    const int cs = tt & 1, ps = cs ^ 1;

    // e-part: token id from LDS, embedding row f32 -> f16 fragments
    const int tk = xlds[lrow][t];
    f16x8 A[16];
    #pragma unroll
    for (int kk = 0; kk < 8; ++kk){
      const float* ep = emb + (size_t)tk * HH + kk * 32 + lgrp * 8;
      const float4 u0 = *(const float4*)ep;
      const float4 u1 = *(const float4*)(ep + 4);
      f16x8 v;
      v[0]=(f16)u0.x; v[1]=(f16)u0.y; v[2]=(f16)u0.z; v[3]=(f16)u0.w;
      v[4]=(f16)u1.x; v[5]=(f16)u1.y; v[6]=(f16)u1.z; v[7]=(f16)u1.w;
      A[kk + 8] = v;
    }

    if (tt > 0){
      const u16 need = (u16)(tt - 1);
      const char* bb = gbase + (size_t)ps * 11264;
      ull vv[5] = {0,0,0,0,0};
      bool gt[5] = {false,false,false,false,false};
      int rem = nu;
      while (rem > 0){
        ull tmp[5];
        #pragma unroll
        for (int i = 0; i < 5; ++i)
          if (i < nu && !gt[i])
            tmp[i] = __hip_atomic_load((const ull*)(bb + uoff[i]),
                                       __ATOMIC_RELAXED, __HIP_MEMORY_SCOPE_AGENT);
        #pragma unroll
        for (int i = 0; i < 5; ++i)
          if (i < nu && !gt[i] && (u16)(tmp[i] >> 48) == need){
            vv[i] = tmp[i]; gt[i] = true; --rem;
          }
        if (rem > 0) __builtin_amdgcn_s_sleep(1);
      }
      #pragma unroll
      for (int i = 0; i < 5; ++i)
        if (i < nu){
          #pragma unroll
          for (int c = 0; c < 3; ++c)
            if (ujb[i] + c < 64)
              himg[ps][urow[i]][uj0[i] + c] =
                __builtin_bit_cast(f16, (u16)(vv[i] >> (16 * c)));
        }
    }
    __syncthreads();   // B1: remote h staged; safe to read himg[ps]

    #pragma unroll
    for (int kk = 0; kk < 8; ++kk)
      A[kk] = *(const f16x8*)&himg[ps][lrow][kk * 32 + lgrp * 8];

    f32x4 ac[4];
    #pragma unroll
    for (int g = 0; g < 4; ++g){ ac[g][0]=0.f; ac[g][1]=0.f; ac[g][2]=0.f; ac[g][3]=0.f; }
    #pragma unroll
    for (int kk = 0; kk < 16; ++kk){
      ac[0] = MFMA16(A[kk], BCAST(B[0][kk]), ac[0]);
      ac[1] = MFMA16(A[kk], BCAST(B[1][kk]), ac[1]);
      ac[2] = MFMA16(A[kk], BCAST(B[2][kk]), ac[2]);
      ac[3] = MFMA16(A[kk], BCAST(B[3][kk]), ac[3]);
    }

    #pragma unroll
    for (int r = 0; r < 4; ++r){
      const float iv = fsig (ac[0][r] + bv[0]);
      const float fv = fsig (ac[1][r] + bv[1]);
      const float gv = ftanh(ac[2][r] + bv[2]);
      const float ov = fsig (ac[3][r] + bv[3]);
      const float cn = fv * c4[r] + iv * gv;
      const float hn = ov * ftanh(cn);
      const bool vld = (t < len4[r]);
      c4[r] = vld ? cn : c4[r];
      h4[r] = vld ? hn : h4[r];
      himg[cs][lgrp * 4 + r][jglob] = (f16)h4[r];
    }
    __syncthreads();   // B2: own h_tt visible to packers

    // pack own quarter: [3x f16 | tag tt] per 8B word, one atomic store each
    char* const ob = gbase + (size_t)cs * 11264;
    #pragma unroll 2
    for (int wd = pw; wd < 22; wd += 16){
      const int j0 = wd * 3;
      const u16 a0 = __builtin_bit_cast(u16, himg[cs][prow][(q << 6) + j0]);
      const u16 a1 = (j0 + 1 < 64) ? __builtin_bit_cast(u16, himg[cs][prow][(q << 6) + j0 + 1]) : (u16)0;
      const u16 a2 = (j0 + 2 < 64) ? __builtin_bit_cast(u16, himg[cs][prow][(q << 6) + j0 + 2]) : (u16)0;
      const ull wv = (ull)a0 | ((ull)a1 << 16) | ((ull)a2 << 32) | ((ull)(u16)tt << 48);
      __hip_atomic_store((ull*)(ob + ((((prow << 2) + q) * 22 + wd) << 3)), wv,
                         __ATOMIC_RELAXED, __HIP_MEMORY_SCOPE_AGENT);
    }
  }

  #pragma unroll
  for (int r = 0; r < 4; ++r){
    const int s = sbase + lgrp * 4 + r;
    sen16[(size_t)((s & 31) * 16 + (s >> 5)) * 512 + dir * 256 + jglob] = (f16)h4[r];
  }
}

// ---------------- layer-1 input GEMM: U1[p][gcol][b] ----------------
__global__ __launch_bounds__(256, 2) void u1_gemm_kernel(
    const f16* __restrict__ sen16, const f16* __restrict__ w16, f16* __restrict__ U1)
{
  const int tid = threadIdx.x;
  const int w = tid >> 6, l = tid & 63, lrow = l & 15, lgrp = l >> 4;
  const int p = blockIdx.x;
  const f16* __restrict__ Wih1 = w16 + OFF_WIH1;

  f16x8 A[16];
  #pragma unroll
  for (int kb = 0; kb < 16; ++kb)
    A[kb] = *(const f16x8*)&sen16[(size_t)(p * 16 + lrow) * 512 + kb * 32 + lgrp * 8];

  for (int tile = 0; tile < 16; ++tile){
    const int col = (w * 16 + tile) * 16 + lrow;
    const f16* wp = Wih1 + (size_t)col * 512 + lgrp * 8;
    f32x4 acc = {0.f,0.f,0.f,0.f};
    #pragma unroll
    for (int kb = 0; kb < 16; ++kb){
      f16x8 bfrag = *(const f16x8*)(wp + kb * 32);
      acc = MFMA16(A[kb], bfrag, acc);
    }
    f16x4 o4;
    #pragma unroll
    for (int r = 0; r < 4; ++r) o4[r] = (f16)acc[r];
    *(f16x4*)&U1[((size_t)p * 1024 + col) * 16 + lgrp * 4] = o4;
  }
}

// ---------------- layer-1 LSTM: 2-WG group, pinned Whh1, tagged exchange ----------------
// grid 9; only bids {0,8} work (same-XCD heuristic; protocol correct regardless).
// WG m owns j-half [m*128, m*128+128); wave w owns 32 j's (2x16 sub-blocks).
__global__ __launch_bounds__(256, 1) void lstm1_kernel(
    const f16* __restrict__ w16, const f16* __restrict__ U1,
    const float* __restrict__ b1, char* __restrict__ tags,
    float* __restrict__ h1)
{
  const int bid = blockIdx.x;
  if (bid & 7) return;                 // keep bids 0 and 8
  const int m = bid >> 3;
  __shared__ f16 himg[2][16][264];
  const int tid = threadIdx.x;
  const int w = tid >> 6, l = tid & 63;
  const int lrow = l & 15, lgrp = l >> 4;
  const f16* __restrict__ Whh = w16 + OFF_WHH1;

  int jg[2];
  jg[0] = m * 128 + w * 32 + lrow;
  jg[1] = jg[0] + 16;

  i32x4 B[4][2][8];
  #pragma unroll
  for (int g = 0; g < 4; ++g)
    #pragma unroll
    for (int p = 0; p < 2; ++p){
      const f16* ph = Whh + (size_t)(g * 256 + jg[p]) * HH + lgrp * 8;
      #pragma unroll
      for (int kk = 0; kk < 8; ++kk) B[g][p][kk] = *(const i32x4*)(ph + kk * 32);
    }
  #pragma unroll
  for (int g = 0; g < 4; ++g)
    #pragma unroll
    for (int p = 0; p < 2; ++p)
      #pragma unroll
      for (int kk = 0; kk < 8; ++kk)
        asm volatile("" : "+v"(B[g][p][kk]));

  float bv[4][2];
  #pragma unroll
  for (int g = 0; g < 4; ++g)
    #pragma unroll
    for (int p = 0; p < 2; ++p) bv[g][p] = b1[g * 256 + jg[p]];

  for (int i = tid; i < 2 * 16 * 264; i += 256) ((f16*)himg)[i] = (f16)0.f;
  __syncthreads();

  // consumer units: remote half, 16 rows x 43 words = 688
  const int nu = (tid < 176) ? 3 : 2;
  int uoff[3], urow[3], uj0[3], ujb[3];
  #pragma unroll
  for (int i = 0; i < 3; ++i){
    int u = tid + (i << 8); if (u > 687) u = 687;
    const int r = u / 43;
    const int wd = u - r * 43;
    uoff[i] = ((((r << 1) + (1 - m)) * 43 + wd) << 3);
    urow[i] = r; ujb[i] = wd * 3; uj0[i] = (1 - m) * 128 + wd * 3;
  }
  const int prow = tid >> 4, pw = tid & 15;

  float c4[2][4] = {}, h4[2][4] = {};

  for (int pt = 0; pt < 32; ++pt){
    const int cs = pt & 1, ps = cs ^ 1;

    f16x4 u[4][2];
    #pragma unroll
    for (int g = 0; g < 4; ++g)
      #pragma unroll
      for (int p = 0; p < 2; ++p)
        u[g][p] = *(const f16x4*)&U1[((size_t)pt * 1024 + g * 256 + jg[p]) * 16 + lgrp * 4];

    if (pt > 0){
      const u16 need = (u16)(pt - 1);
      const char* bb = tags + (size_t)ps * 11008;
      ull vv[3] = {0,0,0};
      bool gt[3] = {false,false,false};
      int rem = nu;
      while (rem > 0){
        ull tmp[3];
        #pragma unroll
        for (int i = 0; i < 3; ++i)
          if (i < nu && !gt[i])
            tmp[i] = __hip_atomic_load((const ull*)(bb + uoff[i]),
                                       __ATOMIC_RELAXED, __HIP_MEMORY_SCOPE_AGENT);
        #pragma unroll
        for (int i = 0; i < 3; ++i)
          if (i < nu && !gt[i] && (u16)(tmp[i] >> 48) == need){
            vv[i] = tmp[i]; gt[i] = true; --rem;
          }
        if (rem > 0) __builtin_amdgcn_s_sleep(1);
      }
      #pragma unroll
      for (int i = 0; i < 3; ++i)
        if (i < nu){
          #pragma unroll
          for (int c = 0; c < 3; ++c)
            if (ujb[i] + c < 128)
              himg[ps][urow[i]][uj0[i] + c] =
                __builtin_bit_cast(f16, (u16)(vv[i] >> (16 * c)));
        }
    }
    __syncthreads();

    f16x8 A[8];
    #pragma unroll
    for (int kk = 0; kk < 8; ++kk)
      A[kk] = *(const f16x8*)&himg[ps][lrow][kk * 32 + lgrp * 8];

    f32x4 ac[4][2];
    #pragma unroll
    for (int g = 0; g < 4; ++g)
      #pragma unroll
      for (int p = 0; p < 2; ++p){ ac[g][p][0]=0.f; ac[g][p][1]=0.f; ac[g][p][2]=0.f; ac[g][p][3]=0.f; }
    #pragma unroll
    for (int kk = 0; kk < 8; ++kk)
      #pragma unroll
      for (int g = 0; g < 4; ++g){
        ac[g][0] = MFMA16(A[kk], BCAST(B[g][0][kk]), ac[g][0]);
        ac[g][1] = MFMA16(A[kk], BCAST(B[g][1][kk]), ac[g][1]);
      }

    #pragma unroll
    for (int p = 0; p < 2; ++p)
      #pragma unroll
      for (int r = 0; r < 4; ++r){
        const float iv = fsig (ac[0][p][r] + (float)u[0][p][r] + bv[0][p]);
        const float fv = fsig (ac[1][p][r] + (float)u[1][p][r] + bv[1][p]);
        const float gv = ftanh(ac[2][p][r] + (float)u[2][p][r] + bv[2][p]);
        const float ov = fsig (ac[3][p][r] + (float)u[3][p][r] + bv[3][p]);
        const float cn = fv * c4[p][r] + iv * gv;
        c4[p][r] = cn;
        h4[p][r] = ov * ftanh(cn);
        himg[cs][lgrp * 4 + r][jg[p]] = (f16)h4[p][r];
      }
    __syncthreads();

    char* const ob = tags + (size_t)cs * 11008;
    #pragma unroll 3
    for (int wd = pw; wd < 43; wd += 16){
      const int j0 = wd * 3;
      const u16 a0 = __builtin_bit_cast(u16, himg[cs][prow][m * 128 + j0]);
      const u16 a1 = (j0 + 1 < 128) ? __builtin_bit_cast(u16, himg[cs][prow][m * 128 + j0 + 1]) : (u16)0;
      const u16 a2 = (j0 + 2 < 128) ? __builtin_bit_cast(u16, himg[cs][prow][m * 128 + j0 + 2]) : (u16)0;
      const ull wv = (ull)a0 | ((ull)a1 << 16) | ((ull)a2 << 32) | ((ull)(u16)pt << 48);
      __hip_atomic_store((ull*)(ob + ((((prow << 1) + m) * 43 + wd) << 3)), wv,
                         __ATOMIC_RELAXED, __HIP_MEMORY_SCOPE_AGENT);
    }
  }

  #pragma unroll
  for (int p = 0; p < 2; ++p)
    #pragma unroll
    for (int r = 0; r < 4; ++r)
      h1[(lgrp * 4 + r) * 256 + jg[p]] = h4[p][r];
}

// ---------------- final FC ----------------
__global__ __launch_bounds__(256) void fc_kernel(const float* __restrict__ h1,
                                                 const float* __restrict__ Wfc,
                                                 const float* __restrict__ bfc,
                                                 float* __restrict__ out){
  __shared__ float hl[16 * 256];
  const int tid = threadIdx.x;
  for (int i = tid; i < 4096; i += 256) hl[i] = h1[i];
  __syncthreads();
  const int o = tid & 127, half = tid >> 7;
  float acc[8];
  #pragma unroll
  for (int i = 0; i < 8; ++i) acc[i] = bfc[o];
  const float* wp = Wfc + (size_t)o * 256;
  for (int j = 0; j < 256; ++j){
    const float wv = wp[j];
    #pragma unroll
    for (int i = 0; i < 8; ++i) acc[i] += wv * hl[(half * 8 + i) * 256 + j];
  }
  #pragma unroll
  for (int i = 0; i < 8; ++i) out[(half * 8 + i) * 128 + o] = acc[i];
}

extern "C" void kernel_launch(void* const* d_in, const int* in_sizes, int n_in,
                              void* d_out, int out_size, void* d_ws, size_t ws_size,
                              hipStream_t stream) {
  if (ws_size < (size_t)WS_NEED) return;

  const int*   x     = (const int*)  d_in[0];
  const int*   xm    = (const int*)  d_in[1];
  const float* emb   = (const float*)d_in[2];
  const float* Wih0f = (const float*)d_in[3];
  const float* Whh0f = (const float*)d_in[4];
  const float* b0f   = (const float*)d_in[5];
  const float* Wih0b = (const float*)d_in[6];
  const float* Whh0b = (const float*)d_in[7];
  const float* b0b   = (const float*)d_in[8];
  const float* Wih1  = (const float*)d_in[9];
  const float* Whh1  = (const float*)d_in[10];
  const float* b1    = (const float*)d_in[11];
  const float* Wfc   = (const float*)d_in[12];
  const float* bfc   = (const float*)d_in[13];
  float* out = (float*)d_out;
  char*  ws  = (char*)d_ws;

  f16*   w16   = (f16*)(ws + WS_W16);
  f16*   sen16 = (f16*)(ws + WS_SEN);
  f16*   U1    = (f16*)(ws + WS_U1);
  float* h1    = (float*)(ws + WS_H1);
  int*   lens  = (int*)(ws + WS_LENS);
  char*  tags0 = ws + WS_TAGS0;
  char*  tags1 = ws + WS_TAGS1;

  cvt_all_kernel<<<1792, 256, 0, stream>>>(Wih0f, Whh0f, Wih0b, Whh0b, Wih1, Whh1, w16);
  lens_kernel<<<512, 64, 0, stream>>>(xm, lens);
  hipMemsetAsync(ws, 0xFF, 1594880, stream);   // tag regions: 0xFFFF never matches a step tag

  lstm0_kernel<<<256, 256, 0, stream>>>(x, emb, w16, b0f, b0b, lens, tags0, sen16);
  u1_gemm_kernel<<<32, 256, 0, stream>>>(sen16, w16, U1);
  lstm1_kernel<<<9, 256, 0, stream>>>(w16, U1, b1, tags1, h1);
  fc_kernel<<<1, 256, 0, stream>>>(h1, Wfc, bfc, out);
}